// Round 1
// baseline (15266.855 us; speedup 1.0000x reference)
//
#include <hip/hip_runtime.h>

#define NN 50000
#define NE 1600000
#define HD 128
#define NL 6
#define EPSV 1e-5f

// ------------------------------------------------------------------ small ----
__global__ void k_prep(const float* __restrict__ dom, const float* __restrict__ t,
                       const float* __restrict__ domn, const float* __restrict__ tn,
                       float* __restrict__ gf) {
  int i = threadIdx.x;
  if (i < 3) gf[i] = dom[i];
  if (i < 2) gf[3 + i] = t[i];
  if (i < 3) gf[5 + i] = domn[i];
  if (i < 2) gf[8 + i] = tn[i];
}

// fold gf columns of each W1 into an effective bias. slots: 0..5 msg, 6..11 upd, 12 emb
__global__ void k_bias(const float* __restrict__ gf,
                       const float* __restrict__ msgW1, const float* __restrict__ msgb1,
                       const float* __restrict__ updW1, const float* __restrict__ updb1,
                       const float* __restrict__ embW1, const float* __restrict__ embb1,
                       float* __restrict__ beff) {
  int s = blockIdx.x, f = threadIdx.x;
  float acc;
  if (s < 6) {
    acc = msgb1[s * HD + f];
    const float* W = msgW1 + (size_t)s * 155 * HD;
    for (int g = 0; g < 10; g++) acc += gf[g] * W[(145 + g) * HD + f];
  } else if (s < 12) {
    int l = s - 6;
    acc = updb1[l * HD + f];
    const float* W = updW1 + (size_t)l * 266 * HD;
    for (int g = 0; g < 10; g++) acc += gf[g] * W[(256 + g) * HD + f];
  } else {
    acc = embb1[f];
    for (int g = 0; g < 10; g++) acc += gf[g] * embW1[(7 + g) * HD + f];
  }
  beff[s * HD + f] = acc;
}

__global__ void k_deg(const int* __restrict__ dst, float* __restrict__ deg) {
  int i = blockIdx.x * blockDim.x + threadIdx.x;
  int stride = gridDim.x * blockDim.x;
  for (; i < NE; i += stride) atomicAdd(&deg[dst[i]], 1.0f);
}

__global__ void k_deginv(float* __restrict__ deg) {
  int i = blockIdx.x * blockDim.x + threadIdx.x;
  if (i < NN) deg[i] = 1.0f / fmaxf(deg[i], 1.0f);
}

// ---------------------------------------------------------------- embed ------
// BN=16 nodes, 256 threads. x0 = [r, v(6)] (gf folded into beff), K=7.
__global__ __launch_bounds__(256) void k_embed(
    const float* __restrict__ v, const float* __restrict__ r,
    const float* __restrict__ W1, const float* __restrict__ b1eff,
    const float* __restrict__ W2, const float* __restrict__ b2,
    float* __restrict__ h) {
  __shared__ float sIn[16][8];
  __shared__ float sW[32][128];
  __shared__ float sH[16][132];
  int tid = threadIdx.x;
  int n0 = blockIdx.x * 16;
  int tx = tid & 63, ty = tid >> 6;
  if (tid < 16 * 7) {
    int n = tid / 7, k = tid - n * 7;
    int gi = n0 + n;
    sIn[n][k] = (k == 0) ? r[gi] : v[gi * 6 + k - 1];
  }
  for (int idx = tid; idx < 7 * 128; idx += 256) sW[idx >> 7][idx & 127] = W1[idx];
  __syncthreads();
  float acc0[4], acc1[4];
  float bb0 = b1eff[tx], bb1 = b1eff[tx + 64];
#pragma unroll
  for (int i = 0; i < 4; i++) { acc0[i] = bb0; acc1[i] = bb1; }
  for (int k = 0; k < 7; k++) {
    float w0 = sW[k][tx], w1 = sW[k][tx + 64];
#pragma unroll
    for (int i = 0; i < 4; i++) {
      float a = sIn[ty * 4 + i][k];
      acc0[i] += a * w0; acc1[i] += a * w1;
    }
  }
  __syncthreads();
#pragma unroll
  for (int i = 0; i < 4; i++) {
    sH[ty * 4 + i][tx] = fmaxf(acc0[i], 0.f);
    sH[ty * 4 + i][tx + 64] = fmaxf(acc1[i], 0.f);
  }
  float bc0 = b2[tx], bc1 = b2[tx + 64];
#pragma unroll
  for (int i = 0; i < 4; i++) { acc0[i] = bc0; acc1[i] = bc1; }
  for (int k0 = 0; k0 < 128; k0 += 32) {
    __syncthreads();
    for (int idx = tid; idx < 32 * 128; idx += 256)
      sW[idx >> 7][idx & 127] = W2[(k0 + (idx >> 7)) * 128 + (idx & 127)];
    __syncthreads();
    for (int kk = 0; kk < 32; kk++) {
      float w0 = sW[kk][tx], w1 = sW[kk][tx + 64];
#pragma unroll
      for (int i = 0; i < 4; i++) {
        float a = sH[ty * 4 + i][k0 + kk];
        acc0[i] += a * w0; acc1[i] += a * w1;
      }
    }
  }
  for (int i = 0; i < 4; i++) {
    int gi = n0 + ty * 4 + i;
    h[gi * 128 + tx] = fmaxf(acc0[i], 0.f);
    h[gi * 128 + tx + 64] = fmaxf(acc1[i], 0.f);
  }
}

// ---------------------------------------------------------------- message ----
// 64 edges/block, 256 threads. Lanes = edges; each wave-uniform group of 32
// features streams W through scalar loads (SGPR operand of v_fma).
__global__ __launch_bounds__(256) void k_msg(
    const float* __restrict__ h, const float* __restrict__ v, const float* __restrict__ r,
    const float* __restrict__ pos, const int* __restrict__ src, const int* __restrict__ dst,
    const float* __restrict__ W1, const float* __restrict__ b1eff,
    const float* __restrict__ W2, const float* __restrict__ b2,
    float* __restrict__ agg) {
  __shared__ float sT[155 * 65];  // [k][e] pad65; reused as hid [f][e], then m [e][f](129)
  __shared__ int sSrc[64], sDst[64];
  int tid = threadIdx.x;
  int e0 = blockIdx.x * 64;
  if (tid < 64) { sSrc[tid] = src[e0 + tid]; sDst[tid] = dst[e0 + tid]; }
  __syncthreads();
  // build transposed m_in rows 0..144 (gf folded into bias)
  for (int idx = tid; idx < 64 * 145; idx += 256) {
    int e = idx / 145, k = idx - e * 145;
    int si = sSrc[e], di = sDst[e];
    float val;
    if (k < 128)       val = h[di * 128 + k] - h[si * 128 + k];
    else if (k < 134)  val = v[di * 6 + (k - 128)];
    else if (k < 140)  val = v[si * 6 + (k - 134)];
    else if (k == 140) val = r[di];
    else if (k == 141) val = r[si];
    else               val = pos[di * 3 + (k - 142)] - pos[si * 3 + (k - 142)];
    sT[k * 65 + e] = val;
  }
  __syncthreads();
  int lane = tid & 63;
  int grp = __builtin_amdgcn_readfirstlane(tid >> 6);  // wave-uniform 0..3
  int f0 = grp * 32;
  float acc[32];
#pragma unroll
  for (int j = 0; j < 32; j++) acc[j] = b1eff[f0 + j];
  for (int k = 0; k < 145; k++) {
    float a = sT[k * 65 + lane];
    const float* Wr = W1 + k * 128 + f0;
#pragma unroll
    for (int j = 0; j < 32; j++) acc[j] += a * Wr[j];
  }
  __syncthreads();
#pragma unroll
  for (int j = 0; j < 32; j++) sT[(f0 + j) * 65 + lane] = fmaxf(acc[j], 0.f);
#pragma unroll
  for (int j = 0; j < 32; j++) acc[j] = b2[f0 + j];
  __syncthreads();
  for (int k = 0; k < 128; k++) {
    float a = sT[k * 65 + lane];
    const float* Wr = W2 + k * 128 + f0;
#pragma unroll
    for (int j = 0; j < 32; j++) acc[j] += a * Wr[j];
  }
  __syncthreads();
#pragma unroll
  for (int j = 0; j < 32; j++) sT[lane * 129 + f0 + j] = fmaxf(acc[j], 0.f);
  __syncthreads();
  // coalesced scatter: threads (f = tid&127, g = tid>>7)
  int f = tid & 127, g = tid >> 7;
  for (int e = g * 32; e < g * 32 + 32; e++) {
    atomicAdd(&agg[(size_t)sDst[e] * 128 + f], sT[e * 129 + f]);
  }
}

// ---------------------------------------------------------------- update -----
// 64 nodes/block, 256 threads. u_in = [h | agg*deginv | gf(folded)].
__global__ __launch_bounds__(256) void k_upd(
    float* __restrict__ h, const float* __restrict__ agg, const float* __restrict__ deginv,
    const float* __restrict__ W1, const float* __restrict__ b1eff,
    const float* __restrict__ W2, const float* __restrict__ b2,
    float* __restrict__ colsum, float* __restrict__ colsumsq) {
  __shared__ float sT[128 * 65];
  int tid = threadIdx.x;
  int n0 = blockIdx.x * 64;
  int lane = tid & 63;
  int grp = __builtin_amdgcn_readfirstlane(tid >> 6);
  int f0 = grp * 32;
  float acc[32];
#pragma unroll
  for (int j = 0; j < 32; j++) acc[j] = b1eff[f0 + j];
  // phase A: agg part (W1 rows 128..255)
  for (int idx = tid; idx < 64 * 128; idx += 256) {
    int n = idx >> 7, k = idx & 127;
    int gi = n0 + n;
    sT[k * 65 + n] = (gi < NN) ? agg[(size_t)gi * 128 + k] * deginv[gi] : 0.f;
  }
  __syncthreads();
  for (int k = 0; k < 128; k++) {
    float a = sT[k * 65 + lane];
    const float* Wr = W1 + (128 + k) * 128 + f0;
#pragma unroll
    for (int j = 0; j < 32; j++) acc[j] += a * Wr[j];
  }
  __syncthreads();
  // phase B: h part (W1 rows 0..127)
  for (int idx = tid; idx < 64 * 128; idx += 256) {
    int n = idx >> 7, k = idx & 127;
    int gi = n0 + n;
    sT[k * 65 + n] = (gi < NN) ? h[(size_t)gi * 128 + k] : 0.f;
  }
  __syncthreads();
  for (int k = 0; k < 128; k++) {
    float a = sT[k * 65 + lane];
    const float* Wr = W1 + k * 128 + f0;
#pragma unroll
    for (int j = 0; j < 32; j++) acc[j] += a * Wr[j];
  }
  // keep my h values (transposed read) before hid overwrites
  float hreg[32];
#pragma unroll
  for (int j = 0; j < 32; j++) hreg[j] = sT[(f0 + j) * 65 + lane];
  __syncthreads();
#pragma unroll
  for (int j = 0; j < 32; j++) sT[(f0 + j) * 65 + lane] = fmaxf(acc[j], 0.f);
#pragma unroll
  for (int j = 0; j < 32; j++) acc[j] = b2[f0 + j];
  __syncthreads();
  for (int k = 0; k < 128; k++) {
    float a = sT[k * 65 + lane];
    const float* Wr = W2 + k * 128 + f0;
#pragma unroll
    for (int j = 0; j < 32; j++) acc[j] += a * Wr[j];
  }
  __syncthreads();
#pragma unroll
  for (int j = 0; j < 32; j++) sT[lane * 129 + f0 + j] = hreg[j] + fmaxf(acc[j], 0.f);
  __syncthreads();
  // writeback + per-feature stats: threads (f = tid&127, g = tid>>7)
  int f = tid & 127, g = tid >> 7;
  float s = 0.f, q = 0.f;
  for (int e = g * 32; e < g * 32 + 32; e++) {
    int gi = n0 + e;
    if (gi < NN) {
      float val = sT[e * 129 + f];
      h[(size_t)gi * 128 + f] = val;
      s += val; q += val * val;
    }
  }
  __syncthreads();
  sT[g * 256 + f] = s;
  sT[g * 256 + 128 + f] = q;
  __syncthreads();
  if (tid < 128) {
    atomicAdd(&colsum[tid], sT[tid] + sT[256 + tid]);
    atomicAdd(&colsumsq[tid], sT[128 + tid] + sT[384 + tid]);
  }
}

__global__ void k_norm(float* __restrict__ h, const float* __restrict__ colsum,
                       const float* __restrict__ colsumsq) {
  int idx = blockIdx.x * blockDim.x + threadIdx.x;
  int f = idx & 127;
  const float invn = 1.0f / (float)NN;
  float mean = colsum[f] * invn;
  float var = colsumsq[f] * invn - mean * mean;
  h[idx] = (h[idx] - mean) * rsqrtf(var + EPSV);
}

// ---------------------------------------------------------------- output -----
__global__ __launch_bounds__(256) void k_out(
    const float* __restrict__ h, const float* __restrict__ pos, const float* __restrict__ v,
    const float* __restrict__ gf,
    const float* __restrict__ W1, const float* __restrict__ b1,
    const float* __restrict__ W2, const float* __restrict__ b2,
    float* __restrict__ out) {
  __shared__ float sH[16][132];
  __shared__ float sW[32][128];
  int tid = threadIdx.x;
  int n0 = blockIdx.x * 16;
  int tx = tid & 63, ty = tid >> 6;
  for (int idx = tid; idx < 16 * 128; idx += 256) {
    int n = idx >> 7, k = idx & 127;
    sH[n][k] = h[(size_t)(n0 + n) * 128 + k];
  }
  float acc0[4], acc1[4];
  float bb0 = b1[tx], bb1 = b1[tx + 64];
#pragma unroll
  for (int i = 0; i < 4; i++) { acc0[i] = bb0; acc1[i] = bb1; }
  for (int k0 = 0; k0 < 128; k0 += 32) {
    __syncthreads();
    for (int idx = tid; idx < 32 * 128; idx += 256)
      sW[idx >> 7][idx & 127] = W1[(k0 + (idx >> 7)) * 128 + (idx & 127)];
    __syncthreads();
    for (int kk = 0; kk < 32; kk++) {
      float w0 = sW[kk][tx], w1 = sW[kk][tx + 64];
#pragma unroll
      for (int i = 0; i < 4; i++) {
        float a = sH[ty * 4 + i][k0 + kk];
        acc0[i] += a * w0; acc1[i] += a * w1;
      }
    }
  }
  __syncthreads();
#pragma unroll
  for (int i = 0; i < 4; i++) {
    sH[ty * 4 + i][tx] = fmaxf(acc0[i], 0.f);
    sH[ty * 4 + i][tx + 64] = fmaxf(acc1[i], 0.f);
  }
  __syncthreads();
  if (tid < 144) {
    int n = tid / 9, j = tid - n * 9;
    float a = b2[j];
    for (int k = 0; k < 128; k++) a += sH[n][k] * W2[k * 9 + j];
    int gi = n0 + n;
    if (j < 3) {
      float p = a + pos[gi * 3 + j];
      float d = gf[5 + j];  // domain_next
      float m = fmodf(p, d);
      if (m < 0.f) m += d;
      out[(size_t)gi * 3 + j] = m;
    } else {
      float p = a + v[gi * 6 + (j - 3)];
      out[(size_t)NN * 3 + (size_t)gi * 6 + (j - 3)] = p;
    }
  }
}

__global__ void k_hsum(const float* __restrict__ h, float* __restrict__ hsum) {
  int f = threadIdx.x;  // 128
  int n0 = blockIdx.x * 512;
  float s = 0.f;
  int nend = n0 + 512 < NN ? n0 + 512 : NN;
  for (int n = n0; n < nend; n++) s += h[(size_t)n * 128 + f];
  atomicAdd(&hsum[f], s);
}

__global__ void k_macro(const float* __restrict__ hsum,
                        const float* __restrict__ W1, const float* __restrict__ b1,
                        const float* __restrict__ W2, const float* __restrict__ b2,
                        float* __restrict__ out) {
  __shared__ float hm[128];
  __shared__ float hid[128];
  int f = threadIdx.x;
  hm[f] = hsum[f] * (1.0f / (float)NN);
  __syncthreads();
  float acc = b1[f];
  for (int k = 0; k < 128; k++) acc += hm[k] * W1[k * 128 + f];
  hid[f] = fmaxf(acc, 0.f);
  __syncthreads();
  if (f < 4) {
    float a = b2[f];
    for (int k = 0; k < 128; k++) a += hid[k] * W2[k * 4 + f];
    out[(size_t)NN * 9 + f] = a;
  }
}

// ------------------------------------------------------------------ host -----
extern "C" void kernel_launch(void* const* d_in, const int* in_sizes, int n_in,
                              void* d_out, int out_size, void* d_ws, size_t ws_size,
                              hipStream_t stream) {
  (void)in_sizes; (void)n_in; (void)out_size; (void)ws_size;
  const float* v    = (const float*)d_in[0];
  const float* pos  = (const float*)d_in[1];
  const float* r    = (const float*)d_in[2];
  const float* dom  = (const float*)d_in[3];
  const float* t    = (const float*)d_in[4];
  const float* domn = (const float*)d_in[5];
  const float* tn   = (const float*)d_in[6];
  const int*   eidx = (const int*)d_in[7];
  // d_in[8] = batch (all zeros, single graph) — unused
  const float* embW1 = (const float*)d_in[9];
  const float* embb1 = (const float*)d_in[10];
  const float* embW2 = (const float*)d_in[11];
  const float* embb2 = (const float*)d_in[12];
  const float* msgW1 = (const float*)d_in[13];
  const float* msgb1 = (const float*)d_in[14];
  const float* msgW2 = (const float*)d_in[15];
  const float* msgb2 = (const float*)d_in[16];
  const float* updW1 = (const float*)d_in[17];
  const float* updb1 = (const float*)d_in[18];
  const float* updW2 = (const float*)d_in[19];
  const float* updb2 = (const float*)d_in[20];
  const float* outW1 = (const float*)d_in[21];
  const float* outb1 = (const float*)d_in[22];
  const float* outW2 = (const float*)d_in[23];
  const float* outb2 = (const float*)d_in[24];
  const float* macW1 = (const float*)d_in[25];
  const float* macb1 = (const float*)d_in[26];
  const float* macW2 = (const float*)d_in[27];
  const float* macb2 = (const float*)d_in[28];

  const int* src = eidx;
  const int* dst = eidx + NE;

  char* ws = (char*)d_ws;
  float* h       = (float*)(ws);                       // NN*128
  float* agg     = (float*)(ws + 25600000);            // NN*128
  float* deg     = (float*)(ws + 51200000);            // NN (becomes deginv)
  float* gf      = (float*)(ws + 51400000);            // 16
  float* beff    = (float*)(ws + 51400064);            // 13*128
  float* colsum  = (float*)(ws + 51406720);            // 128
  float* colsumsq= (float*)(ws + 51407232);            // 128
  float* hsum    = (float*)(ws + 51407744);            // 128
  float* outp    = (float*)d_out;

  k_prep<<<1, 64, 0, stream>>>(dom, t, domn, tn, gf);
  k_bias<<<13, 128, 0, stream>>>(gf, msgW1, msgb1, updW1, updb1, embW1, embb1, beff);

  hipMemsetAsync(deg, 0, NN * sizeof(float), stream);
  k_deg<<<4096, 256, 0, stream>>>(dst, deg);
  k_deginv<<<(NN + 255) / 256, 256, 0, stream>>>(deg);

  k_embed<<<NN / 16, 256, 0, stream>>>(v, r, embW1, beff + 12 * HD, embW2, embb2, h);

  for (int l = 0; l < NL; l++) {
    hipMemsetAsync(agg, 0, (size_t)NN * 128 * sizeof(float), stream);
    hipMemsetAsync(colsum, 0, 1024, stream);  // colsum + colsumsq contiguous
    k_msg<<<NE / 64, 256, 0, stream>>>(h, v, r, pos, src, dst,
                                       msgW1 + (size_t)l * 155 * HD, beff + l * HD,
                                       msgW2 + (size_t)l * HD * HD, msgb2 + l * HD, agg);
    k_upd<<<(NN + 63) / 64, 256, 0, stream>>>(h, agg, deg,
                                              updW1 + (size_t)l * 266 * HD, beff + (6 + l) * HD,
                                              updW2 + (size_t)l * HD * HD, updb2 + l * HD,
                                              colsum, colsumsq);
    k_norm<<<NN * HD / 256, 256, 0, stream>>>(h, colsum, colsumsq);
  }

  hipMemsetAsync(hsum, 0, 512, stream);
  k_hsum<<<(NN + 511) / 512, 128, 0, stream>>>(h, hsum);
  k_out<<<NN / 16, 256, 0, stream>>>(h, pos, v, gf, outW1, outb1, outW2, outb2, outp);
  k_macro<<<1, 128, 0, stream>>>(hsum, macW1, macb1, macW2, macb2, outp);
}

// Round 2
// 8454.771 us; speedup vs baseline: 1.8057x; 1.8057x over previous
//
#include <hip/hip_runtime.h>

#define NN 50000
#define NE 1600000
#define HD 128
#define NL 6
#define EPSV 1e-5f
#define KP 168  // padded fp16 row stride for A tiles

typedef _Float16 h8 __attribute__((ext_vector_type(8)));
typedef float f4 __attribute__((ext_vector_type(4)));

// ------------------------------------------------------------------ small ----
__global__ void k_prep(const float* __restrict__ dom, const float* __restrict__ t,
                       const float* __restrict__ domn, const float* __restrict__ tn,
                       float* __restrict__ gf) {
  int i = threadIdx.x;
  if (i < 3) gf[i] = dom[i];
  if (i < 2) gf[3 + i] = t[i];
  if (i < 3) gf[5 + i] = domn[i];
  if (i < 2) gf[8 + i] = tn[i];
}

// fold gf columns of each W1 into an effective bias. slots: 0..5 msg, 6..11 upd, 12 emb
__global__ void k_bias(const float* __restrict__ gf,
                       const float* __restrict__ msgW1, const float* __restrict__ msgb1,
                       const float* __restrict__ updW1, const float* __restrict__ updb1,
                       const float* __restrict__ embW1, const float* __restrict__ embb1,
                       float* __restrict__ beff) {
  int s = blockIdx.x, f = threadIdx.x;
  float acc;
  if (s < 6) {
    acc = msgb1[s * HD + f];
    const float* W = msgW1 + (size_t)s * 155 * HD;
    for (int g = 0; g < 10; g++) acc += gf[g] * W[(145 + g) * HD + f];
  } else if (s < 12) {
    int l = s - 6;
    acc = updb1[l * HD + f];
    const float* W = updW1 + (size_t)l * 266 * HD;
    for (int g = 0; g < 10; g++) acc += gf[g] * W[(256 + g) * HD + f];
  } else {
    acc = embb1[f];
    for (int g = 0; g < 10; g++) acc += gf[g] * embW1[(7 + g) * HD + f];
  }
  beff[s * HD + f] = acc;
}

// pack msg weights into split-fp16 MFMA fragment order.
// per layer: 72 fragpairs (W1: ks*8+nt for ks<5; W2: 40 + ks*8+nt for ks<4)
// fragpair = [hi: 64 lanes x 8 halfs][lo: 64 lanes x 8 halfs] = 1024 halfs
// slot convention: lane l, elem j  ->  k = ks*32 + 8*(l>>4) + j, col = nt*16 + (l&15)
__global__ void k_wpack(const float* __restrict__ msgW1, const float* __restrict__ msgW2,
                        _Float16* __restrict__ wpack) {
  int b = blockIdx.x;          // 6*9*8 = 432 blocks
  int nt = b & 7;
  int rest = b >> 3;
  int part = rest % 9;
  int layer = rest / 9;
  int lane = threadIdx.x;      // 64
  int g = lane >> 4, c = lane & 15;
  const float* W; int Ksrc, ks, fp;
  if (part < 5) { W = msgW1 + (size_t)layer * 155 * HD; Ksrc = 145; ks = part; fp = ks * 8 + nt; }
  else          { W = msgW2 + (size_t)layer * HD * HD;  Ksrc = 128; ks = part - 5; fp = 40 + ks * 8 + nt; }
  h8 hv, lv;
#pragma unroll
  for (int j = 0; j < 8; j++) {
    int k = ks * 32 + 8 * g + j;
    float w = (k < Ksrc) ? W[(size_t)k * HD + nt * 16 + c] : 0.f;
    _Float16 hi = (_Float16)w;
    hv[j] = hi;
    lv[j] = (_Float16)(w - (float)hi);
  }
  _Float16* base = wpack + (size_t)layer * 73728 + (size_t)fp * 1024;
  *(h8*)(base + lane * 8) = hv;
  *(h8*)(base + 512 + lane * 8) = lv;
}

__global__ void k_deg(const int* __restrict__ dst, float* __restrict__ deg) {
  int i = blockIdx.x * blockDim.x + threadIdx.x;
  int stride = gridDim.x * blockDim.x;
  for (; i < NE; i += stride) atomicAdd(&deg[dst[i]], 1.0f);
}

__global__ void k_deginv(float* __restrict__ deg) {
  int i = blockIdx.x * blockDim.x + threadIdx.x;
  if (i < NN) deg[i] = 1.0f / fmaxf(deg[i], 1.0f);
}

// ---------------------------------------------------------------- embed ------
__global__ __launch_bounds__(256) void k_embed(
    const float* __restrict__ v, const float* __restrict__ r,
    const float* __restrict__ W1, const float* __restrict__ b1eff,
    const float* __restrict__ W2, const float* __restrict__ b2,
    float* __restrict__ h) {
  __shared__ float sIn[16][8];
  __shared__ float sW[32][128];
  __shared__ float sH[16][132];
  int tid = threadIdx.x;
  int n0 = blockIdx.x * 16;
  int tx = tid & 63, ty = tid >> 6;
  if (tid < 16 * 7) {
    int n = tid / 7, k = tid - n * 7;
    int gi = n0 + n;
    sIn[n][k] = (k == 0) ? r[gi] : v[gi * 6 + k - 1];
  }
  for (int idx = tid; idx < 7 * 128; idx += 256) sW[idx >> 7][idx & 127] = W1[idx];
  __syncthreads();
  float acc0[4], acc1[4];
  float bb0 = b1eff[tx], bb1 = b1eff[tx + 64];
#pragma unroll
  for (int i = 0; i < 4; i++) { acc0[i] = bb0; acc1[i] = bb1; }
  for (int k = 0; k < 7; k++) {
    float w0 = sW[k][tx], w1 = sW[k][tx + 64];
#pragma unroll
    for (int i = 0; i < 4; i++) {
      float a = sIn[ty * 4 + i][k];
      acc0[i] += a * w0; acc1[i] += a * w1;
    }
  }
  __syncthreads();
#pragma unroll
  for (int i = 0; i < 4; i++) {
    sH[ty * 4 + i][tx] = fmaxf(acc0[i], 0.f);
    sH[ty * 4 + i][tx + 64] = fmaxf(acc1[i], 0.f);
  }
  float bc0 = b2[tx], bc1 = b2[tx + 64];
#pragma unroll
  for (int i = 0; i < 4; i++) { acc0[i] = bc0; acc1[i] = bc1; }
  for (int k0 = 0; k0 < 128; k0 += 32) {
    __syncthreads();
    for (int idx = tid; idx < 32 * 128; idx += 256)
      sW[idx >> 7][idx & 127] = W2[(k0 + (idx >> 7)) * 128 + (idx & 127)];
    __syncthreads();
    for (int kk = 0; kk < 32; kk++) {
      float w0 = sW[kk][tx], w1 = sW[kk][tx + 64];
#pragma unroll
      for (int i = 0; i < 4; i++) {
        float a = sH[ty * 4 + i][k0 + kk];
        acc0[i] += a * w0; acc1[i] += a * w1;
      }
    }
  }
  for (int i = 0; i < 4; i++) {
    int gi = n0 + ty * 4 + i;
    h[gi * 128 + tx] = fmaxf(acc0[i], 0.f);
    h[gi * 128 + tx + 64] = fmaxf(acc1[i], 0.f);
  }
}

// ---------------------------------------------------------------- message ----
// MFMA split-fp16. 512 threads = 8 waves; 64 edges/block; wave w owns cols [16w,16w+16).
__global__ __launch_bounds__(512, 4) void k_msg2(
    const float* __restrict__ h, const float* __restrict__ v, const float* __restrict__ r,
    const float* __restrict__ pos, const int* __restrict__ src, const int* __restrict__ dst,
    const _Float16* __restrict__ wl, const float* __restrict__ b1eff,
    const float* __restrict__ b2, float* __restrict__ agg) {
  __shared__ char smem[43008 + 512];
  _Float16* Ahi = (_Float16*)smem;           // [64][KP]
  _Float16* Alo = Ahi + 64 * KP;             // [64][KP]
  float* sM = (float*)smem;                  // [64][132] overlay (after GEMM2)
  int* sSrc = (int*)(smem + 43008);
  int* sDst = sSrc + 64;

  int tid = threadIdx.x;
  int lane = tid & 63;
  int wid = __builtin_amdgcn_readfirstlane(tid >> 6);  // 0..7
  int e0 = blockIdx.x * 64;

  // W1 fragments (issued early; overlap with edge-index load + gather)
  h8 w1hi[5], w1lo[5];
#pragma unroll
  for (int ks = 0; ks < 5; ks++) {
    const _Float16* p = wl + (ks * 8 + wid) * 1024 + lane * 8;
    w1hi[ks] = *(const h8*)p;
    w1lo[ks] = *(const h8*)(p + 512);
  }
  float b1v = b1eff[wid * 16 + (lane & 15)];
  float b2v = b2[wid * 16 + (lane & 15)];

  if (tid < 64) { sSrc[tid] = src[e0 + tid]; sDst[tid] = dst[e0 + tid]; }
  __syncthreads();

  // build m_in split-fp16: h-diff part (k=0..127)
  for (int idx = tid; idx < 64 * 128; idx += 512) {
    int e = idx >> 7, k = idx & 127;
    int si = sSrc[e], di = sDst[e];
    float d = h[di * 128 + k] - h[si * 128 + k];
    _Float16 hi = (_Float16)d;
    Ahi[e * KP + k] = hi;
    Alo[e * KP + k] = (_Float16)(d - (float)hi);
  }
  // rest (k=128..159; zeros beyond 144)
  for (int idx = tid; idx < 64 * 32; idx += 512) {
    int e = idx >> 5, kk = idx & 31;
    int si = sSrc[e], di = sDst[e];
    float val;
    if (kk < 6)        val = v[di * 6 + kk];
    else if (kk < 12)  val = v[si * 6 + (kk - 6)];
    else if (kk == 12) val = r[di];
    else if (kk == 13) val = r[si];
    else if (kk < 17)  val = pos[di * 3 + (kk - 14)] - pos[si * 3 + (kk - 14)];
    else               val = 0.f;
    _Float16 hi = (_Float16)val;
    Ahi[e * KP + 128 + kk] = hi;
    Alo[e * KP + 128 + kk] = (_Float16)(val - (float)hi);
  }
  __syncthreads();

  // GEMM1: hidden(64x16 per wave) = m_in(64x160) @ W1(160x16)
  int arow = lane & 15;
  int acol = 8 * (lane >> 4);
  f4 acc[4];
#pragma unroll
  for (int mt = 0; mt < 4; mt++) acc[mt] = (f4){b1v, b1v, b1v, b1v};
#pragma unroll
  for (int ks = 0; ks < 5; ks++) {
#pragma unroll
    for (int mt = 0; mt < 4; mt++) {
      h8 ahi = *(const h8*)&Ahi[(mt * 16 + arow) * KP + ks * 32 + acol];
      h8 alo = *(const h8*)&Alo[(mt * 16 + arow) * KP + ks * 32 + acol];
      acc[mt] = __builtin_amdgcn_mfma_f32_16x16x32_f16(ahi, w1hi[ks], acc[mt], 0, 0, 0);
      acc[mt] = __builtin_amdgcn_mfma_f32_16x16x32_f16(ahi, w1lo[ks], acc[mt], 0, 0, 0);
      acc[mt] = __builtin_amdgcn_mfma_f32_16x16x32_f16(alo, w1hi[ks], acc[mt], 0, 0, 0);
    }
  }
  // W2 fragments (issue before barrier; consumed after next sync)
  h8 w2hi[4], w2lo[4];
#pragma unroll
  for (int ks = 0; ks < 4; ks++) {
    const _Float16* p = wl + (40 + ks * 8 + wid) * 1024 + lane * 8;
    w2hi[ks] = *(const h8*)p;
    w2lo[ks] = *(const h8*)(p + 512);
  }
  __syncthreads();  // all GEMM1 A-reads done

  // write relu(hidden) back as split-fp16 A2 tile [64][128]
  int drow0 = 4 * (lane >> 4);
  int dcol = wid * 16 + (lane & 15);
#pragma unroll
  for (int mt = 0; mt < 4; mt++) {
#pragma unroll
    for (int i = 0; i < 4; i++) {
      float hv = fmaxf(acc[mt][i], 0.f);
      int row = mt * 16 + drow0 + i;
      _Float16 hi = (_Float16)hv;
      Ahi[row * KP + dcol] = hi;
      Alo[row * KP + dcol] = (_Float16)(hv - (float)hi);
    }
  }
  __syncthreads();

  // GEMM2: m(64x16 per wave) = hidden(64x128) @ W2(128x16)
#pragma unroll
  for (int mt = 0; mt < 4; mt++) acc[mt] = (f4){b2v, b2v, b2v, b2v};
#pragma unroll
  for (int ks = 0; ks < 4; ks++) {
#pragma unroll
    for (int mt = 0; mt < 4; mt++) {
      h8 ahi = *(const h8*)&Ahi[(mt * 16 + arow) * KP + ks * 32 + acol];
      h8 alo = *(const h8*)&Alo[(mt * 16 + arow) * KP + ks * 32 + acol];
      acc[mt] = __builtin_amdgcn_mfma_f32_16x16x32_f16(ahi, w2hi[ks], acc[mt], 0, 0, 0);
      acc[mt] = __builtin_amdgcn_mfma_f32_16x16x32_f16(ahi, w2lo[ks], acc[mt], 0, 0, 0);
      acc[mt] = __builtin_amdgcn_mfma_f32_16x16x32_f16(alo, w2hi[ks], acc[mt], 0, 0, 0);
    }
  }
  __syncthreads();  // all GEMM2 A-reads done before sM overlay

#pragma unroll
  for (int mt = 0; mt < 4; mt++) {
#pragma unroll
    for (int i = 0; i < 4; i++) {
      sM[(mt * 16 + drow0 + i) * 132 + dcol] = fmaxf(acc[mt][i], 0.f);
    }
  }
  __syncthreads();

  // coalesced scatter: f contiguous per wave-half
  int f = tid & 127, grp = tid >> 7;  // 4 groups x 16 edges
  for (int e = grp * 16; e < grp * 16 + 16; e++) {
    atomicAdd(&agg[(size_t)sDst[e] * 128 + f], sM[e * 132 + f]);
  }
}

// ---------------------------------------------------------------- update -----
__global__ __launch_bounds__(256) void k_upd(
    float* __restrict__ h, const float* __restrict__ agg, const float* __restrict__ deginv,
    const float* __restrict__ W1, const float* __restrict__ b1eff,
    const float* __restrict__ W2, const float* __restrict__ b2,
    float* __restrict__ colsum, float* __restrict__ colsumsq) {
  __shared__ float sT[128 * 65];
  int tid = threadIdx.x;
  int n0 = blockIdx.x * 64;
  int lane = tid & 63;
  int grp = __builtin_amdgcn_readfirstlane(tid >> 6);
  int f0 = grp * 32;
  float acc[32];
#pragma unroll
  for (int j = 0; j < 32; j++) acc[j] = b1eff[f0 + j];
  for (int idx = tid; idx < 64 * 128; idx += 256) {
    int n = idx >> 7, k = idx & 127;
    int gi = n0 + n;
    sT[k * 65 + n] = (gi < NN) ? agg[(size_t)gi * 128 + k] * deginv[gi] : 0.f;
  }
  __syncthreads();
  for (int k = 0; k < 128; k++) {
    float a = sT[k * 65 + lane];
    const float* Wr = W1 + (128 + k) * 128 + f0;
#pragma unroll
    for (int j = 0; j < 32; j++) acc[j] += a * Wr[j];
  }
  __syncthreads();
  for (int idx = tid; idx < 64 * 128; idx += 256) {
    int n = idx >> 7, k = idx & 127;
    int gi = n0 + n;
    sT[k * 65 + n] = (gi < NN) ? h[(size_t)gi * 128 + k] : 0.f;
  }
  __syncthreads();
  for (int k = 0; k < 128; k++) {
    float a = sT[k * 65 + lane];
    const float* Wr = W1 + k * 128 + f0;
#pragma unroll
    for (int j = 0; j < 32; j++) acc[j] += a * Wr[j];
  }
  float hreg[32];
#pragma unroll
  for (int j = 0; j < 32; j++) hreg[j] = sT[(f0 + j) * 65 + lane];
  __syncthreads();
#pragma unroll
  for (int j = 0; j < 32; j++) sT[(f0 + j) * 65 + lane] = fmaxf(acc[j], 0.f);
#pragma unroll
  for (int j = 0; j < 32; j++) acc[j] = b2[f0 + j];
  __syncthreads();
  for (int k = 0; k < 128; k++) {
    float a = sT[k * 65 + lane];
    const float* Wr = W2 + k * 128 + f0;
#pragma unroll
    for (int j = 0; j < 32; j++) acc[j] += a * Wr[j];
  }
  __syncthreads();
#pragma unroll
  for (int j = 0; j < 32; j++) sT[lane * 129 + f0 + j] = hreg[j] + fmaxf(acc[j], 0.f);
  __syncthreads();
  int f = tid & 127, g = tid >> 7;
  float s = 0.f, q = 0.f;
  for (int e = g * 32; e < g * 32 + 32; e++) {
    int gi = n0 + e;
    if (gi < NN) {
      float val = sT[e * 129 + f];
      h[(size_t)gi * 128 + f] = val;
      s += val; q += val * val;
    }
  }
  __syncthreads();
  sT[g * 256 + f] = s;
  sT[g * 256 + 128 + f] = q;
  __syncthreads();
  if (tid < 128) {
    atomicAdd(&colsum[tid], sT[tid] + sT[256 + tid]);
    atomicAdd(&colsumsq[tid], sT[128 + tid] + sT[384 + tid]);
  }
}

__global__ void k_norm(float* __restrict__ h, const float* __restrict__ colsum,
                       const float* __restrict__ colsumsq) {
  int idx = blockIdx.x * blockDim.x + threadIdx.x;
  int f = idx & 127;
  const float invn = 1.0f / (float)NN;
  float mean = colsum[f] * invn;
  float var = colsumsq[f] * invn - mean * mean;
  h[idx] = (h[idx] - mean) * rsqrtf(var + EPSV);
}

// ---------------------------------------------------------------- output -----
__global__ __launch_bounds__(256) void k_out(
    const float* __restrict__ h, const float* __restrict__ pos, const float* __restrict__ v,
    const float* __restrict__ gf,
    const float* __restrict__ W1, const float* __restrict__ b1,
    const float* __restrict__ W2, const float* __restrict__ b2,
    float* __restrict__ out) {
  __shared__ float sH[16][132];
  __shared__ float sW[32][128];
  int tid = threadIdx.x;
  int n0 = blockIdx.x * 16;
  int tx = tid & 63, ty = tid >> 6;
  for (int idx = tid; idx < 16 * 128; idx += 256) {
    int n = idx >> 7, k = idx & 127;
    sH[n][k] = h[(size_t)(n0 + n) * 128 + k];
  }
  float acc0[4], acc1[4];
  float bb0 = b1[tx], bb1 = b1[tx + 64];
#pragma unroll
  for (int i = 0; i < 4; i++) { acc0[i] = bb0; acc1[i] = bb1; }
  for (int k0 = 0; k0 < 128; k0 += 32) {
    __syncthreads();
    for (int idx = tid; idx < 32 * 128; idx += 256)
      sW[idx >> 7][idx & 127] = W1[(k0 + (idx >> 7)) * 128 + (idx & 127)];
    __syncthreads();
    for (int kk = 0; kk < 32; kk++) {
      float w0 = sW[kk][tx], w1 = sW[kk][tx + 64];
#pragma unroll
      for (int i = 0; i < 4; i++) {
        float a = sH[ty * 4 + i][k0 + kk];
        acc0[i] += a * w0; acc1[i] += a * w1;
      }
    }
  }
  __syncthreads();
#pragma unroll
  for (int i = 0; i < 4; i++) {
    sH[ty * 4 + i][tx] = fmaxf(acc0[i], 0.f);
    sH[ty * 4 + i][tx + 64] = fmaxf(acc1[i], 0.f);
  }
  __syncthreads();
  if (tid < 144) {
    int n = tid / 9, j = tid - n * 9;
    float a = b2[j];
    for (int k = 0; k < 128; k++) a += sH[n][k] * W2[k * 9 + j];
    int gi = n0 + n;
    if (j < 3) {
      float p = a + pos[gi * 3 + j];
      float d = gf[5 + j];
      float m = fmodf(p, d);
      if (m < 0.f) m += d;
      out[(size_t)gi * 3 + j] = m;
    } else {
      float p = a + v[gi * 6 + (j - 3)];
      out[(size_t)NN * 3 + (size_t)gi * 6 + (j - 3)] = p;
    }
  }
}

__global__ void k_hsum(const float* __restrict__ h, float* __restrict__ hsum) {
  int f = threadIdx.x;
  int n0 = blockIdx.x * 512;
  float s = 0.f;
  int nend = n0 + 512 < NN ? n0 + 512 : NN;
  for (int n = n0; n < nend; n++) s += h[(size_t)n * 128 + f];
  atomicAdd(&hsum[f], s);
}

__global__ void k_macro(const float* __restrict__ hsum,
                        const float* __restrict__ W1, const float* __restrict__ b1,
                        const float* __restrict__ W2, const float* __restrict__ b2,
                        float* __restrict__ out) {
  __shared__ float hm[128];
  __shared__ float hid[128];
  int f = threadIdx.x;
  hm[f] = hsum[f] * (1.0f / (float)NN);
  __syncthreads();
  float acc = b1[f];
  for (int k = 0; k < 128; k++) acc += hm[k] * W1[k * 128 + f];
  hid[f] = fmaxf(acc, 0.f);
  __syncthreads();
  if (f < 4) {
    float a = b2[f];
    for (int k = 0; k < 128; k++) a += hid[k] * W2[k * 4 + f];
    out[(size_t)NN * 9 + f] = a;
  }
}

// ------------------------------------------------------------------ host -----
extern "C" void kernel_launch(void* const* d_in, const int* in_sizes, int n_in,
                              void* d_out, int out_size, void* d_ws, size_t ws_size,
                              hipStream_t stream) {
  (void)in_sizes; (void)n_in; (void)out_size; (void)ws_size;
  const float* v    = (const float*)d_in[0];
  const float* pos  = (const float*)d_in[1];
  const float* r    = (const float*)d_in[2];
  const float* dom  = (const float*)d_in[3];
  const float* t    = (const float*)d_in[4];
  const float* domn = (const float*)d_in[5];
  const float* tn   = (const float*)d_in[6];
  const int*   eidx = (const int*)d_in[7];
  const float* embW1 = (const float*)d_in[9];
  const float* embb1 = (const float*)d_in[10];
  const float* embW2 = (const float*)d_in[11];
  const float* embb2 = (const float*)d_in[12];
  const float* msgW1 = (const float*)d_in[13];
  const float* msgb1 = (const float*)d_in[14];
  const float* msgW2 = (const float*)d_in[15];
  const float* msgb2 = (const float*)d_in[16];
  const float* updW1 = (const float*)d_in[17];
  const float* updb1 = (const float*)d_in[18];
  const float* updW2 = (const float*)d_in[19];
  const float* updb2 = (const float*)d_in[20];
  const float* outW1 = (const float*)d_in[21];
  const float* outb1 = (const float*)d_in[22];
  const float* outW2 = (const float*)d_in[23];
  const float* outb2 = (const float*)d_in[24];
  const float* macW1 = (const float*)d_in[25];
  const float* macb1 = (const float*)d_in[26];
  const float* macW2 = (const float*)d_in[27];
  const float* macb2 = (const float*)d_in[28];

  const int* src = eidx;
  const int* dst = eidx + NE;

  char* ws = (char*)d_ws;
  float* h        = (float*)(ws);                  // NN*128 f32
  float* agg      = (float*)(ws + 25600000);       // NN*128 f32
  float* deg      = (float*)(ws + 51200000);       // NN f32
  float* gf       = (float*)(ws + 51400064);       // 16
  float* beff     = (float*)(ws + 51400192);       // 13*128
  float* colsum   = (float*)(ws + 51406848);       // 128
  float* colsumsq = (float*)(ws + 51407360);       // 128
  float* hsum     = (float*)(ws + 51407872);       // 128
  _Float16* wpack = (_Float16*)(ws + 51408896);    // 6*73728 halfs = 884736 B
  float* outp     = (float*)d_out;

  k_prep<<<1, 64, 0, stream>>>(dom, t, domn, tn, gf);
  k_bias<<<13, 128, 0, stream>>>(gf, msgW1, msgb1, updW1, updb1, embW1, embb1, beff);
  k_wpack<<<432, 64, 0, stream>>>(msgW1, msgW2, wpack);

  hipMemsetAsync(deg, 0, NN * sizeof(float), stream);
  k_deg<<<4096, 256, 0, stream>>>(dst, deg);
  k_deginv<<<(NN + 255) / 256, 256, 0, stream>>>(deg);

  k_embed<<<NN / 16, 256, 0, stream>>>(v, r, embW1, beff + 12 * HD, embW2, embb2, h);

  for (int l = 0; l < NL; l++) {
    hipMemsetAsync(agg, 0, (size_t)NN * 128 * sizeof(float), stream);
    hipMemsetAsync(colsum, 0, 1024, stream);
    k_msg2<<<NE / 64, 512, 0, stream>>>(h, v, r, pos, src, dst,
                                        wpack + (size_t)l * 73728, beff + l * HD,
                                        msgb2 + l * HD, agg);
    k_upd<<<(NN + 63) / 64, 256, 0, stream>>>(h, agg, deg,
                                              updW1 + (size_t)l * 266 * HD, beff + (6 + l) * HD,
                                              updW2 + (size_t)l * HD * HD, updb2 + l * HD,
                                              colsum, colsumsq);
    k_norm<<<NN * HD / 256, 256, 0, stream>>>(h, colsum, colsumsq);
  }

  hipMemsetAsync(hsum, 0, 512, stream);
  k_hsum<<<(NN + 511) / 512, 128, 0, stream>>>(h, hsum);
  k_out<<<NN / 16, 256, 0, stream>>>(h, pos, v, gf, outW1, outb1, outW2, outb2, outp);
  k_macro<<<1, 128, 0, stream>>>(hsum, macW1, macb1, macW2, macb2, outp);
}

// Round 3
// 2793.726 us; speedup vs baseline: 5.4647x; 3.0263x over previous
//
#include <hip/hip_runtime.h>

#define NN 50000
#define NE 1600000
#define HD 128
#define NL 6
#define EPSV 1e-5f

typedef _Float16 h8 __attribute__((ext_vector_type(8)));
typedef float f4 __attribute__((ext_vector_type(4)));

// ------------------------------------------------------------------ small ----
__global__ void k_prep(const float* __restrict__ dom, const float* __restrict__ t,
                       const float* __restrict__ domn, const float* __restrict__ tn,
                       float* __restrict__ gf) {
  int i = threadIdx.x;
  if (i < 3) gf[i] = dom[i];
  if (i < 2) gf[3 + i] = t[i];
  if (i < 3) gf[5 + i] = domn[i];
  if (i < 2) gf[8 + i] = tn[i];
}

// fold gf columns of each W1 into an effective bias. slots: 0..5 msg, 6..11 upd, 12 emb
__global__ void k_bias(const float* __restrict__ gf,
                       const float* __restrict__ msgW1, const float* __restrict__ msgb1,
                       const float* __restrict__ updW1, const float* __restrict__ updb1,
                       const float* __restrict__ embW1, const float* __restrict__ embb1,
                       float* __restrict__ beff) {
  int s = blockIdx.x, f = threadIdx.x;
  float acc;
  if (s < 6) {
    acc = msgb1[s * HD + f];
    const float* W = msgW1 + (size_t)s * 155 * HD;
    for (int g = 0; g < 10; g++) acc += gf[g] * W[(145 + g) * HD + f];
  } else if (s < 12) {
    int l = s - 6;
    acc = updb1[l * HD + f];
    const float* W = updW1 + (size_t)l * 266 * HD;
    for (int g = 0; g < 10; g++) acc += gf[g] * W[(256 + g) * HD + f];
  } else {
    acc = embb1[f];
    for (int g = 0; g < 10; g++) acc += gf[g] * embW1[(7 + g) * HD + f];
  }
  beff[s * HD + f] = acc;
}

// pack msg weights into split-fp16 MFMA fragment order.
// frag (ks,nt): W1 rows ks*32.. at fp=ks*8+nt (ks<5); W2 at 40+ks*8+nt (ks<4)
// slot: lane l, elem j -> k = ks*32 + 8*(l>>4) + j, col = nt*16 + (l&15)
__global__ void k_wpack(const float* __restrict__ msgW1, const float* __restrict__ msgW2,
                        _Float16* __restrict__ wpack) {
  int b = blockIdx.x;          // 6*9*8 = 432
  int nt = b & 7;
  int rest = b >> 3;
  int part = rest % 9;
  int layer = rest / 9;
  int lane = threadIdx.x;
  int g = lane >> 4, c = lane & 15;
  const float* W; int Ksrc, ks, fp;
  if (part < 5) { W = msgW1 + (size_t)layer * 155 * HD; Ksrc = 145; ks = part; fp = ks * 8 + nt; }
  else          { W = msgW2 + (size_t)layer * HD * HD;  Ksrc = 128; ks = part - 5; fp = 40 + ks * 8 + nt; }
  h8 hv, lv;
#pragma unroll
  for (int j = 0; j < 8; j++) {
    int k = ks * 32 + 8 * g + j;
    float w = (k < Ksrc) ? W[(size_t)k * HD + nt * 16 + c] : 0.f;
    _Float16 hi = (_Float16)w;
    hv[j] = hi;
    lv[j] = (_Float16)(w - (float)hi);
  }
  _Float16* base = wpack + (size_t)layer * 73728 + (size_t)fp * 1024;
  *(h8*)(base + lane * 8) = hv;
  *(h8*)(base + 512 + lane * 8) = lv;
}

// ---------------------------------------------------------- CSR build --------
__global__ void k_degi(const int* __restrict__ dst, int* __restrict__ degi) {
  int i = blockIdx.x * blockDim.x + threadIdx.x;
  int stride = gridDim.x * blockDim.x;
  for (; i < NE; i += stride) atomicAdd(&degi[dst[i]], 1);
}

__global__ void k_deginv(const int* __restrict__ degi, float* __restrict__ deginv) {
  int i = blockIdx.x * blockDim.x + threadIdx.x;
  if (i < NN) deginv[i] = 1.0f / (float)max(degi[i], 1);
}

// single block, 1024 threads: exclusive prefix of degi -> cursor
__global__ __launch_bounds__(1024) void k_scan(const int* __restrict__ degi,
                                               int* __restrict__ cursor) {
  __shared__ int ps[1024];
  int t = threadIdx.x;
  const int CH = 49;  // 1024*49 >= NN
  int lo = t * CH, hi = min(lo + CH, NN);
  int s = 0;
  for (int i = lo; i < hi; i++) s += degi[i];
  ps[t] = s;
  __syncthreads();
  for (int d = 1; d < 1024; d <<= 1) {
    int vv = (t >= d) ? ps[t - d] : 0;
    __syncthreads();
    ps[t] += vv;
    __syncthreads();
  }
  int base = (t > 0) ? ps[t - 1] : 0;
  for (int i = lo; i < hi; i++) { cursor[i] = base; base += degi[i]; }
}

__global__ void k_scatter(const int* __restrict__ src, const int* __restrict__ dst,
                          int* __restrict__ cursor, unsigned long long* __restrict__ es8) {
  int i = blockIdx.x * blockDim.x + threadIdx.x;
  int stride = gridDim.x * blockDim.x;
  for (; i < NE; i += stride) {
    int d = dst[i];
    int p = atomicAdd(&cursor[d], 1);
    es8[p] = ((unsigned long long)(unsigned)d << 32) | (unsigned)src[i];
  }
}

// ---------------------------------------------------------------- embed ------
__global__ __launch_bounds__(256) void k_embed(
    const float* __restrict__ v, const float* __restrict__ r,
    const float* __restrict__ W1, const float* __restrict__ b1eff,
    const float* __restrict__ W2, const float* __restrict__ b2,
    float* __restrict__ h) {
  __shared__ float sIn[16][8];
  __shared__ float sW[32][128];
  __shared__ float sH[16][132];
  int tid = threadIdx.x;
  int n0 = blockIdx.x * 16;
  int tx = tid & 63, ty = tid >> 6;
  if (tid < 16 * 7) {
    int n = tid / 7, k = tid - n * 7;
    int gi = n0 + n;
    sIn[n][k] = (k == 0) ? r[gi] : v[gi * 6 + k - 1];
  }
  for (int idx = tid; idx < 7 * 128; idx += 256) sW[idx >> 7][idx & 127] = W1[idx];
  __syncthreads();
  float acc0[4], acc1[4];
  float bb0 = b1eff[tx], bb1 = b1eff[tx + 64];
#pragma unroll
  for (int i = 0; i < 4; i++) { acc0[i] = bb0; acc1[i] = bb1; }
  for (int k = 0; k < 7; k++) {
    float w0 = sW[k][tx], w1 = sW[k][tx + 64];
#pragma unroll
    for (int i = 0; i < 4; i++) {
      float a = sIn[ty * 4 + i][k];
      acc0[i] += a * w0; acc1[i] += a * w1;
    }
  }
  __syncthreads();
#pragma unroll
  for (int i = 0; i < 4; i++) {
    sH[ty * 4 + i][tx] = fmaxf(acc0[i], 0.f);
    sH[ty * 4 + i][tx + 64] = fmaxf(acc1[i], 0.f);
  }
  float bc0 = b2[tx], bc1 = b2[tx + 64];
#pragma unroll
  for (int i = 0; i < 4; i++) { acc0[i] = bc0; acc1[i] = bc1; }
  for (int k0 = 0; k0 < 128; k0 += 32) {
    __syncthreads();
    for (int idx = tid; idx < 32 * 128; idx += 256)
      sW[idx >> 7][idx & 127] = W2[(k0 + (idx >> 7)) * 128 + (idx & 127)];
    __syncthreads();
    for (int kk = 0; kk < 32; kk++) {
      float w0 = sW[kk][tx], w1 = sW[kk][tx + 64];
#pragma unroll
      for (int i = 0; i < 4; i++) {
        float a = sH[ty * 4 + i][k0 + kk];
        acc0[i] += a * w0; acc1[i] += a * w1;
      }
    }
  }
  for (int i = 0; i < 4; i++) {
    int gi = n0 + ty * 4 + i;
    h[gi * 128 + tx] = fmaxf(acc0[i], 0.f);
    h[gi * 128 + tx + 64] = fmaxf(acc1[i], 0.f);
  }
}

// ------------------------------------------------------------- node U/V ------
// U = h@W1h + Qd + b1eff ; V = -h@W1h + Qs. 64 nodes/block, 512 threads.
__global__ __launch_bounds__(512) void k_uv(
    const float* __restrict__ h, const float* __restrict__ v, const float* __restrict__ r,
    const float* __restrict__ pos,
    const _Float16* __restrict__ wl, const float* __restrict__ W1,
    const float* __restrict__ b1eff,
    float* __restrict__ U, float* __restrict__ Vv) {
  __shared__ char smem[32768];     // Ahi 16KB | Alo 16KB, swizzled, row stride 256B
  __shared__ float sW1s[17][128];  // W1 rows 128..144
  __shared__ float sNode[64][10];  // v(6), r(1), pos(3)
  int tid = threadIdx.x;
  int lane = tid & 63;
  int wid = __builtin_amdgcn_readfirstlane(tid >> 6);
  int n0 = blockIdx.x * 64;

  // stage W1 small rows + node data
  for (int idx = tid; idx < 17 * 128; idx += 512)
    sW1s[idx >> 7][idx & 127] = W1[(128 + (idx >> 7)) * HD + (idx & 127)];
  for (int idx = tid; idx < 640; idx += 512) {
    int n = idx / 10, j = idx - n * 10;
    int gn = n0 + n;
    float val = 0.f;
    if (gn < NN) val = (j < 6) ? v[gn * 6 + j] : (j == 6) ? r[gn] : pos[gn * 3 + (j - 7)];
    sNode[n][j] = val;
  }
  // stage split-fp16 h tile (swizzled)
#pragma unroll
  for (int it = 0; it < 2; it++) {
    int idx = tid + it * 512;
    int n = idx >> 4, kg = idx & 15;
    int gn = n0 + n;
    float4 a0 = {0,0,0,0}, a1 = {0,0,0,0};
    if (gn < NN) {
      const float4* hp = (const float4*)(h + (size_t)gn * 128 + kg * 8);
      a0 = hp[0]; a1 = hp[1];
    }
    h8 hi, lo;
#define SPLH(s, x) { float pv = (x); _Float16 hh = (_Float16)pv; hi[s] = hh; lo[s] = (_Float16)(pv - (float)hh); }
    SPLH(0, a0.x) SPLH(1, a0.y) SPLH(2, a0.z) SPLH(3, a0.w)
    SPLH(4, a1.x) SPLH(5, a1.y) SPLH(6, a1.z) SPLH(7, a1.w)
#undef SPLH
    int byteoff = (n * 256 + kg * 16) ^ ((n & 7) << 4);
    *(h8*)(smem + byteoff) = hi;
    *(h8*)(smem + 16384 + byteoff) = lo;
  }
  __syncthreads();

  // GEMM: P = h @ W1h, wave wid owns cols wid*16..+16
  h8 w1hi[4], w1lo[4];
#pragma unroll
  for (int ks = 0; ks < 4; ks++) {
    const _Float16* p = wl + (size_t)(ks * 8 + wid) * 1024 + lane * 8;
    w1hi[ks] = *(const h8*)p;
    w1lo[ks] = *(const h8*)(p + 512);
  }
  int arow = lane & 15, g4 = lane >> 4;
  f4 acc[4];
#pragma unroll
  for (int mt = 0; mt < 4; mt++) acc[mt] = (f4){0.f, 0.f, 0.f, 0.f};
#pragma unroll
  for (int ks = 0; ks < 4; ks++) {
#pragma unroll
    for (int mt = 0; mt < 4; mt++) {
      int row = mt * 16 + arow;
      int byte = (row * 256 + ks * 64 + g4 * 16) ^ ((row & 7) << 4);
      h8 ahi = *(const h8*)(smem + byte);
      h8 alo = *(const h8*)(smem + 16384 + byte);
      acc[mt] = __builtin_amdgcn_mfma_f32_16x16x32_f16(ahi, w1hi[ks], acc[mt], 0, 0, 0);
      acc[mt] = __builtin_amdgcn_mfma_f32_16x16x32_f16(ahi, w1lo[ks], acc[mt], 0, 0, 0);
      acc[mt] = __builtin_amdgcn_mfma_f32_16x16x32_f16(alo, w1hi[ks], acc[mt], 0, 0, 0);
    }
  }
  // epilogue: U/V
  int cc = wid * 16 + (lane & 15);
  float b1v = b1eff[cc];
#pragma unroll
  for (int mt = 0; mt < 4; mt++) {
#pragma unroll
    for (int i = 0; i < 4; i++) {
      int n = mt * 16 + 4 * g4 + i;
      int gn = n0 + n;
      if (gn < NN) {
        float P = acc[mt][i];
        float qd = b1v, qs = 0.f;
#pragma unroll
        for (int j = 0; j < 6; j++) {
          float nv = sNode[n][j];
          qd += nv * sW1s[j][cc];
          qs += nv * sW1s[6 + j][cc];
        }
        float nr = sNode[n][6];
        qd += nr * sW1s[12][cc];
        qs += nr * sW1s[13][cc];
#pragma unroll
        for (int j = 0; j < 3; j++) {
          float pq = sNode[n][7 + j] * sW1s[14 + j][cc];
          qd += pq; qs -= pq;
        }
        U[(size_t)gn * 128 + cc] = P + qd;
        Vv[(size_t)gn * 128 + cc] = qs - P;
      }
    }
  }
}

// ---------------------------------------------------------------- message ----
// 128 sorted edges/block, 512 threads. pre = U[dst]+V[src]; m = relu(relu(pre)@W2+b2);
// register-dedupe scatter into agg.
__global__ __launch_bounds__(512, 4) void k_msg3(
    const float* __restrict__ U, const float* __restrict__ Vv,
    const unsigned long long* __restrict__ es8,
    const _Float16* __restrict__ wl, const float* __restrict__ b2,
    float* __restrict__ agg) {
  __shared__ char smem[67584];   // A2hi 32KB | A2lo 32KB ; overlay sM[128][132] f32
  __shared__ int sSrcA[128], sDstA[128];
  float* sM = (float*)smem;
  int tid = threadIdx.x;
  int lane = tid & 63;
  int wid = __builtin_amdgcn_readfirstlane(tid >> 6);
  int e0 = blockIdx.x * 128;

  if (tid < 128) {
    unsigned long long w = es8[(size_t)e0 + tid];
    sSrcA[tid] = (int)(w & 0xffffffffULL);
    sDstA[tid] = (int)(w >> 32);
  }
  // W2 frags for this wave's 32 cols
  int cq = wid & 3;
  h8 w2hi[4][2], w2lo[4][2];
#pragma unroll
  for (int ks = 0; ks < 4; ks++)
#pragma unroll
    for (int nt = 0; nt < 2; nt++) {
      const _Float16* p = wl + (size_t)(40 + ks * 8 + cq * 2 + nt) * 1024 + lane * 8;
      w2hi[ks][nt] = *(const h8*)p;
      w2lo[ks][nt] = *(const h8*)(p + 512);
    }
  __syncthreads();

  // stage A2 = split(relu(U[dst] + V[src])), swizzled
#pragma unroll
  for (int it = 0; it < 4; it++) {
    int idx = tid + it * 512;
    int e = idx >> 4, kg = idx & 15;
    int dd = sDstA[e], ss = sSrcA[e];
    const float4* up = (const float4*)(U + (size_t)dd * 128 + kg * 8);
    const float4* vp = (const float4*)(Vv + (size_t)ss * 128 + kg * 8);
    float4 u0 = up[0], u1 = up[1];
    float4 v0 = vp[0], v1 = vp[1];
    h8 hi, lo;
#define SPL(s, x) { float pre = fmaxf((x), 0.f); _Float16 hh = (_Float16)pre; hi[s] = hh; lo[s] = (_Float16)(pre - (float)hh); }
    SPL(0, u0.x + v0.x) SPL(1, u0.y + v0.y) SPL(2, u0.z + v0.z) SPL(3, u0.w + v0.w)
    SPL(4, u1.x + v1.x) SPL(5, u1.y + v1.y) SPL(6, u1.z + v1.z) SPL(7, u1.w + v1.w)
#undef SPL
    int byteoff = (e * 256 + kg * 16) ^ ((e & 7) << 4);
    *(h8*)(smem + byteoff) = hi;
    *(h8*)(smem + 32768 + byteoff) = lo;
  }
  __syncthreads();

  // GEMM2: wave (eh = wid>>2) edges eh*64.., cols cq*32..
  int eh = wid >> 2;
  int arow = lane & 15, g4 = lane >> 4;
  float b2v0 = b2[cq * 32 + arow];
  float b2v1 = b2[cq * 32 + 16 + arow];
  f4 acc[4][2];
#pragma unroll
  for (int mt = 0; mt < 4; mt++) {
    acc[mt][0] = (f4){b2v0, b2v0, b2v0, b2v0};
    acc[mt][1] = (f4){b2v1, b2v1, b2v1, b2v1};
  }
#pragma unroll
  for (int ks = 0; ks < 4; ks++) {
#pragma unroll
    for (int mt = 0; mt < 4; mt++) {
      int row = eh * 64 + mt * 16 + arow;
      int byte = (row * 256 + ks * 64 + g4 * 16) ^ ((row & 7) << 4);
      h8 ahi = *(const h8*)(smem + byte);
      h8 alo = *(const h8*)(smem + 32768 + byte);
#pragma unroll
      for (int nt = 0; nt < 2; nt++) {
        acc[mt][nt] = __builtin_amdgcn_mfma_f32_16x16x32_f16(ahi, w2hi[ks][nt], acc[mt][nt], 0, 0, 0);
        acc[mt][nt] = __builtin_amdgcn_mfma_f32_16x16x32_f16(ahi, w2lo[ks][nt], acc[mt][nt], 0, 0, 0);
        acc[mt][nt] = __builtin_amdgcn_mfma_f32_16x16x32_f16(alo, w2hi[ks][nt], acc[mt][nt], 0, 0, 0);
      }
    }
  }
  __syncthreads();  // A2 reads done; overlay sM
#pragma unroll
  for (int mt = 0; mt < 4; mt++)
#pragma unroll
    for (int nt = 0; nt < 2; nt++)
#pragma unroll
      for (int i = 0; i < 4; i++) {
        int row = eh * 64 + mt * 16 + 4 * g4 + i;
        int col = cq * 32 + nt * 16 + arow;
        sM[row * 132 + col] = fmaxf(acc[mt][nt][i], 0.f);
      }
  __syncthreads();

  // register-dedupe scatter (edges sorted by dst)
  int f = tid & 127, g = tid >> 7;
  float racc = 0.f;
  int prev = -1;
  for (int e = g * 32; e < g * 32 + 32; e++) {
    int d = sDstA[e];
    if (d != prev) {
      if (prev >= 0) atomicAdd(&agg[(size_t)prev * 128 + f], racc);
      racc = 0.f;
      prev = d;
    }
    racc += sM[e * 132 + f];
  }
  atomicAdd(&agg[(size_t)prev * 128 + f], racc);
}

// ---------------------------------------------------------------- update -----
__global__ __launch_bounds__(256) void k_upd(
    float* __restrict__ h, const float* __restrict__ agg, const float* __restrict__ deginv,
    const float* __restrict__ W1, const float* __restrict__ b1eff,
    const float* __restrict__ W2, const float* __restrict__ b2,
    float* __restrict__ colsum, float* __restrict__ colsumsq) {
  __shared__ float sT[128 * 65];
  int tid = threadIdx.x;
  int n0 = blockIdx.x * 64;
  int lane = tid & 63;
  int grp = __builtin_amdgcn_readfirstlane(tid >> 6);
  int f0 = grp * 32;
  float acc[32];
#pragma unroll
  for (int j = 0; j < 32; j++) acc[j] = b1eff[f0 + j];
  for (int idx = tid; idx < 64 * 128; idx += 256) {
    int n = idx >> 7, k = idx & 127;
    int gi = n0 + n;
    sT[k * 65 + n] = (gi < NN) ? agg[(size_t)gi * 128 + k] * deginv[gi] : 0.f;
  }
  __syncthreads();
  for (int k = 0; k < 128; k++) {
    float a = sT[k * 65 + lane];
    const float* Wr = W1 + (128 + k) * 128 + f0;
#pragma unroll
    for (int j = 0; j < 32; j++) acc[j] += a * Wr[j];
  }
  __syncthreads();
  for (int idx = tid; idx < 64 * 128; idx += 256) {
    int n = idx >> 7, k = idx & 127;
    int gi = n0 + n;
    sT[k * 65 + n] = (gi < NN) ? h[(size_t)gi * 128 + k] : 0.f;
  }
  __syncthreads();
  for (int k = 0; k < 128; k++) {
    float a = sT[k * 65 + lane];
    const float* Wr = W1 + k * 128 + f0;
#pragma unroll
    for (int j = 0; j < 32; j++) acc[j] += a * Wr[j];
  }
  float hreg[32];
#pragma unroll
  for (int j = 0; j < 32; j++) hreg[j] = sT[(f0 + j) * 65 + lane];
  __syncthreads();
#pragma unroll
  for (int j = 0; j < 32; j++) sT[(f0 + j) * 65 + lane] = fmaxf(acc[j], 0.f);
#pragma unroll
  for (int j = 0; j < 32; j++) acc[j] = b2[f0 + j];
  __syncthreads();
  for (int k = 0; k < 128; k++) {
    float a = sT[k * 65 + lane];
    const float* Wr = W2 + k * 128 + f0;
#pragma unroll
    for (int j = 0; j < 32; j++) acc[j] += a * Wr[j];
  }
  __syncthreads();
#pragma unroll
  for (int j = 0; j < 32; j++) sT[lane * 129 + f0 + j] = hreg[j] + fmaxf(acc[j], 0.f);
  __syncthreads();
  int f = tid & 127, g = tid >> 7;
  float s = 0.f, q = 0.f;
  for (int e = g * 32; e < g * 32 + 32; e++) {
    int gi = n0 + e;
    if (gi < NN) {
      float val = sT[e * 129 + f];
      h[(size_t)gi * 128 + f] = val;
      s += val; q += val * val;
    }
  }
  __syncthreads();
  sT[g * 256 + f] = s;
  sT[g * 256 + 128 + f] = q;
  __syncthreads();
  if (tid < 128) {
    atomicAdd(&colsum[tid], sT[tid] + sT[256 + tid]);
    atomicAdd(&colsumsq[tid], sT[128 + tid] + sT[384 + tid]);
  }
}

__global__ void k_norm(float* __restrict__ h, const float* __restrict__ colsum,
                       const float* __restrict__ colsumsq) {
  int idx = blockIdx.x * blockDim.x + threadIdx.x;
  int f = idx & 127;
  const float invn = 1.0f / (float)NN;
  float mean = colsum[f] * invn;
  float var = colsumsq[f] * invn - mean * mean;
  h[idx] = (h[idx] - mean) * rsqrtf(var + EPSV);
}

// ---------------------------------------------------------------- output -----
__global__ __launch_bounds__(256) void k_out(
    const float* __restrict__ h, const float* __restrict__ pos, const float* __restrict__ v,
    const float* __restrict__ gf,
    const float* __restrict__ W1, const float* __restrict__ b1,
    const float* __restrict__ W2, const float* __restrict__ b2,
    float* __restrict__ out) {
  __shared__ float sH[16][132];
  __shared__ float sW[32][128];
  int tid = threadIdx.x;
  int n0 = blockIdx.x * 16;
  int tx = tid & 63, ty = tid >> 6;
  for (int idx = tid; idx < 16 * 128; idx += 256) {
    int n = idx >> 7, k = idx & 127;
    sH[n][k] = h[(size_t)(n0 + n) * 128 + k];
  }
  float acc0[4], acc1[4];
  float bb0 = b1[tx], bb1 = b1[tx + 64];
#pragma unroll
  for (int i = 0; i < 4; i++) { acc0[i] = bb0; acc1[i] = bb1; }
  for (int k0 = 0; k0 < 128; k0 += 32) {
    __syncthreads();
    for (int idx = tid; idx < 32 * 128; idx += 256)
      sW[idx >> 7][idx & 127] = W1[(k0 + (idx >> 7)) * 128 + (idx & 127)];
    __syncthreads();
    for (int kk = 0; kk < 32; kk++) {
      float w0 = sW[kk][tx], w1 = sW[kk][tx + 64];
#pragma unroll
      for (int i = 0; i < 4; i++) {
        float a = sH[ty * 4 + i][k0 + kk];
        acc0[i] += a * w0; acc1[i] += a * w1;
      }
    }
  }
  __syncthreads();
#pragma unroll
  for (int i = 0; i < 4; i++) {
    sH[ty * 4 + i][tx] = fmaxf(acc0[i], 0.f);
    sH[ty * 4 + i][tx + 64] = fmaxf(acc1[i], 0.f);
  }
  __syncthreads();
  if (tid < 144) {
    int n = tid / 9, j = tid - n * 9;
    float a = b2[j];
    for (int k = 0; k < 128; k++) a += sH[n][k] * W2[k * 9 + j];
    int gi = n0 + n;
    if (j < 3) {
      float p = a + pos[gi * 3 + j];
      float d = gf[5 + j];
      float m = fmodf(p, d);
      if (m < 0.f) m += d;
      out[(size_t)gi * 3 + j] = m;
    } else {
      float p = a + v[gi * 6 + (j - 3)];
      out[(size_t)NN * 3 + (size_t)gi * 6 + (j - 3)] = p;
    }
  }
}

__global__ void k_hsum(const float* __restrict__ h, float* __restrict__ hsum) {
  int f = threadIdx.x;
  int n0 = blockIdx.x * 512;
  float s = 0.f;
  int nend = n0 + 512 < NN ? n0 + 512 : NN;
  for (int n = n0; n < nend; n++) s += h[(size_t)n * 128 + f];
  atomicAdd(&hsum[f], s);
}

__global__ void k_macro(const float* __restrict__ hsum,
                        const float* __restrict__ W1, const float* __restrict__ b1,
                        const float* __restrict__ W2, const float* __restrict__ b2,
                        float* __restrict__ out) {
  __shared__ float hm[128];
  __shared__ float hid[128];
  int f = threadIdx.x;
  hm[f] = hsum[f] * (1.0f / (float)NN);
  __syncthreads();
  float acc = b1[f];
  for (int k = 0; k < 128; k++) acc += hm[k] * W1[k * 128 + f];
  hid[f] = fmaxf(acc, 0.f);
  __syncthreads();
  if (f < 4) {
    float a = b2[f];
    for (int k = 0; k < 128; k++) a += hid[k] * W2[k * 4 + f];
    out[(size_t)NN * 9 + f] = a;
  }
}

// ------------------------------------------------------------------ host -----
extern "C" void kernel_launch(void* const* d_in, const int* in_sizes, int n_in,
                              void* d_out, int out_size, void* d_ws, size_t ws_size,
                              hipStream_t stream) {
  (void)in_sizes; (void)n_in; (void)out_size; (void)ws_size;
  const float* v    = (const float*)d_in[0];
  const float* pos  = (const float*)d_in[1];
  const float* r    = (const float*)d_in[2];
  const float* dom  = (const float*)d_in[3];
  const float* t    = (const float*)d_in[4];
  const float* domn = (const float*)d_in[5];
  const float* tn   = (const float*)d_in[6];
  const int*   eidx = (const int*)d_in[7];
  const float* embW1 = (const float*)d_in[9];
  const float* embb1 = (const float*)d_in[10];
  const float* embW2 = (const float*)d_in[11];
  const float* embb2 = (const float*)d_in[12];
  const float* msgW1 = (const float*)d_in[13];
  const float* msgb1 = (const float*)d_in[14];
  const float* msgW2 = (const float*)d_in[15];
  const float* msgb2 = (const float*)d_in[16];
  const float* updW1 = (const float*)d_in[17];
  const float* updb1 = (const float*)d_in[18];
  const float* updW2 = (const float*)d_in[19];
  const float* updb2 = (const float*)d_in[20];
  const float* outW1 = (const float*)d_in[21];
  const float* outb1 = (const float*)d_in[22];
  const float* outW2 = (const float*)d_in[23];
  const float* outb2 = (const float*)d_in[24];
  const float* macW1 = (const float*)d_in[25];
  const float* macb1 = (const float*)d_in[26];
  const float* macW2 = (const float*)d_in[27];
  const float* macb2 = (const float*)d_in[28];

  const int* srcp = eidx;
  const int* dstp = eidx + NE;

  char* ws = (char*)d_ws;
  float* h        = (float*)(ws);                   // 25.6 MB
  float* agg      = (float*)(ws + 25600000);        // 25.6 MB
  float* U        = (float*)(ws + 51200000);        // 25.6 MB
  float* Vv       = (float*)(ws + 76800000);        // 25.6 MB
  unsigned long long* es8 = (unsigned long long*)(ws + 102400000);  // 12.8 MB
  int*   degi     = (int*)(ws + 115200000);         // 200 KB
  float* deginv   = (float*)(ws + 115400000);       // 200 KB
  int*   cursor   = (int*)(ws + 115600000);         // 200 KB
  float* gf       = (float*)(ws + 115800000);       // 64 B
  float* beff     = (float*)(ws + 115800064);       // 6656 B
  float* colsum   = (float*)(ws + 115806720);       // 512 B
  float* colsumsq = (float*)(ws + 115807232);       // 512 B
  float* hsum     = (float*)(ws + 115807744);       // 512 B
  _Float16* wpack = (_Float16*)(ws + 115808256);    // 884736 B
  float* outp     = (float*)d_out;

  k_prep<<<1, 64, 0, stream>>>(dom, t, domn, tn, gf);
  k_bias<<<13, 128, 0, stream>>>(gf, msgW1, msgb1, updW1, updb1, embW1, embb1, beff);
  k_wpack<<<432, 64, 0, stream>>>(msgW1, msgW2, wpack);

  hipMemsetAsync(degi, 0, NN * sizeof(int), stream);
  k_degi<<<4096, 256, 0, stream>>>(dstp, degi);
  k_deginv<<<(NN + 255) / 256, 256, 0, stream>>>(degi, deginv);
  k_scan<<<1, 1024, 0, stream>>>(degi, cursor);
  k_scatter<<<6250, 256, 0, stream>>>(srcp, dstp, cursor, es8);

  k_embed<<<NN / 16, 256, 0, stream>>>(v, r, embW1, beff + 12 * HD, embW2, embb2, h);

  for (int l = 0; l < NL; l++) {
    k_uv<<<(NN + 63) / 64, 512, 0, stream>>>(h, v, r, pos,
                                             wpack + (size_t)l * 73728,
                                             msgW1 + (size_t)l * 155 * HD,
                                             beff + l * HD, U, Vv);
    hipMemsetAsync(agg, 0, (size_t)NN * 128 * sizeof(float), stream);
    hipMemsetAsync(colsum, 0, 1024, stream);
    k_msg3<<<NE / 128, 512, 0, stream>>>(U, Vv, es8,
                                         wpack + (size_t)l * 73728,
                                         msgb2 + l * HD, agg);
    k_upd<<<(NN + 63) / 64, 256, 0, stream>>>(h, agg, deginv,
                                              updW1 + (size_t)l * 266 * HD, beff + (6 + l) * HD,
                                              updW2 + (size_t)l * HD * HD, updb2 + l * HD,
                                              colsum, colsumsq);
    k_norm<<<NN * HD / 256, 256, 0, stream>>>(h, colsum, colsumsq);
  }

  hipMemsetAsync(hsum, 0, 512, stream);
  k_hsum<<<(NN + 511) / 512, 128, 0, stream>>>(h, hsum);
  k_out<<<NN / 16, 256, 0, stream>>>(h, pos, v, gf, outW1, outb1, outW2, outb2, outp);
  k_macro<<<1, 128, 0, stream>>>(hsum, macW1, macb1, macW2, macb2, outp);
}

// Round 5
// 2164.190 us; speedup vs baseline: 7.0543x; 1.2909x over previous
//
#include <hip/hip_runtime.h>

#define NN 50000
#define NE 1600000
#define HD 128
#define NL 6
#define EPSV 1e-5f
#define UPD_OFF 442368  // halfs: 6 layers * 72 fragpairs * 1024

typedef _Float16 h8 __attribute__((ext_vector_type(8)));
typedef float f4 __attribute__((ext_vector_type(4)));

// ------------------------------------------------------------------ small ----
__global__ void k_prep(const float* __restrict__ dom, const float* __restrict__ t,
                       const float* __restrict__ domn, const float* __restrict__ tn,
                       float* __restrict__ gf) {
  int i = threadIdx.x;
  if (i < 3) gf[i] = dom[i];
  if (i < 2) gf[3 + i] = t[i];
  if (i < 3) gf[5 + i] = domn[i];
  if (i < 2) gf[8 + i] = tn[i];
}

__global__ void k_initnorm(float* __restrict__ mean, float* __restrict__ rsig) {
  int f = threadIdx.x;
  mean[f] = 0.f; rsig[f] = 1.f;
}

__global__ void k_stats(const float* __restrict__ colsum, const float* __restrict__ colsumsq,
                        float* __restrict__ mean, float* __restrict__ rsig) {
  int f = threadIdx.x;
  float m = colsum[f] * (1.f / (float)NN);
  float var = colsumsq[f] * (1.f / (float)NN) - m * m;
  mean[f] = m;
  rsig[f] = rsqrtf(var + EPSV);
}

// fold gf columns of each W1 into an effective bias. slots: 0..5 msg, 6..11 upd, 12 emb
__global__ void k_bias(const float* __restrict__ gf,
                       const float* __restrict__ msgW1, const float* __restrict__ msgb1,
                       const float* __restrict__ updW1, const float* __restrict__ updb1,
                       const float* __restrict__ embW1, const float* __restrict__ embb1,
                       float* __restrict__ beff) {
  int s = blockIdx.x, f = threadIdx.x;
  float acc;
  if (s < 6) {
    acc = msgb1[s * HD + f];
    const float* W = msgW1 + (size_t)s * 155 * HD;
    for (int g = 0; g < 10; g++) acc += gf[g] * W[(145 + g) * HD + f];
  } else if (s < 12) {
    int l = s - 6;
    acc = updb1[l * HD + f];
    const float* W = updW1 + (size_t)l * 266 * HD;
    for (int g = 0; g < 10; g++) acc += gf[g] * W[(256 + g) * HD + f];
  } else {
    acc = embb1[f];
    for (int g = 0; g < 10; g++) acc += gf[g] * embW1[(7 + g) * HD + f];
  }
  beff[s * HD + f] = acc;
}

// pack weights into split-fp16 MFMA fragment order (hi 512 halfs, lo 512 halfs).
// slot: lane l, elem j -> k = ks*32 + 8*(l>>4) + j, col = nt*16 + (l&15)
// msg layer base = layer*73728:  W1 fp=ks*8+nt (ks<5), W2 fp=40+ks*8+nt (ks<4)
// upd layer base = UPD_OFF + layer*98304: W1 fp=ks*8+nt (ks<8), W2 fp=64+ks*8+nt (ks<4)
__global__ void k_wpack(const float* __restrict__ msgW1, const float* __restrict__ msgW2,
                        const float* __restrict__ updW1, const float* __restrict__ updW2,
                        _Float16* __restrict__ wpack) {
  int b = blockIdx.x;          // 6*21*8 = 1008
  int nt = b & 7;
  int rest = b >> 3;
  int part = rest % 21;
  int layer = rest / 21;
  int lane = threadIdx.x;
  int g = lane >> 4, c = lane & 15;
  const float* W; int Ksrc, ks; size_t base;
  if (part < 5)       { W = msgW1 + (size_t)layer * 155 * HD; Ksrc = 145; ks = part;
                        base = (size_t)layer * 73728 + (size_t)(ks * 8 + nt) * 1024; }
  else if (part < 9)  { W = msgW2 + (size_t)layer * HD * HD;  Ksrc = 128; ks = part - 5;
                        base = (size_t)layer * 73728 + (size_t)(40 + ks * 8 + nt) * 1024; }
  else if (part < 17) { W = updW1 + (size_t)layer * 266 * HD; Ksrc = 256; ks = part - 9;
                        base = UPD_OFF + (size_t)layer * 98304 + (size_t)(ks * 8 + nt) * 1024; }
  else                { W = updW2 + (size_t)layer * HD * HD;  Ksrc = 128; ks = part - 17;
                        base = UPD_OFF + (size_t)layer * 98304 + (size_t)(64 + ks * 8 + nt) * 1024; }
  h8 hv, lv;
#pragma unroll
  for (int j = 0; j < 8; j++) {
    int k = ks * 32 + 8 * g + j;
    float w = (k < Ksrc) ? W[(size_t)k * HD + nt * 16 + c] : 0.f;
    _Float16 hi = (_Float16)w;
    hv[j] = hi;
    lv[j] = (_Float16)(w - (float)hi);
  }
  _Float16* bp = wpack + base;
  *(h8*)(bp + lane * 8) = hv;
  *(h8*)(bp + 512 + lane * 8) = lv;
}

// ---------------------------------------------------------- CSR build --------
__global__ void k_degi(const int* __restrict__ dst, int* __restrict__ degi) {
  int i = blockIdx.x * blockDim.x + threadIdx.x;
  int stride = gridDim.x * blockDim.x;
  for (; i < NE; i += stride) atomicAdd(&degi[dst[i]], 1);
}

__global__ void k_deginv(const int* __restrict__ degi, float* __restrict__ deginv) {
  int i = blockIdx.x * blockDim.x + threadIdx.x;
  if (i < NN) deginv[i] = 1.0f / (float)max(degi[i], 1);
}

__global__ __launch_bounds__(1024) void k_scan(const int* __restrict__ degi,
                                               int* __restrict__ cursor) {
  __shared__ int ps[1024];
  int t = threadIdx.x;
  const int CH = 49;
  int lo = t * CH, hi = min(lo + CH, NN);
  int s = 0;
  for (int i = lo; i < hi; i++) s += degi[i];
  ps[t] = s;
  __syncthreads();
  for (int d = 1; d < 1024; d <<= 1) {
    int vv = (t >= d) ? ps[t - d] : 0;
    __syncthreads();
    ps[t] += vv;
    __syncthreads();
  }
  int base = (t > 0) ? ps[t - 1] : 0;
  for (int i = lo; i < hi; i++) { cursor[i] = base; base += degi[i]; }
}

__global__ void k_scatter(const int* __restrict__ src, const int* __restrict__ dst,
                          int* __restrict__ cursor, unsigned long long* __restrict__ es8) {
  int i = blockIdx.x * blockDim.x + threadIdx.x;
  int stride = gridDim.x * blockDim.x;
  for (; i < NE; i += stride) {
    int d = dst[i];
    int p = atomicAdd(&cursor[d], 1);
    es8[p] = ((unsigned long long)(unsigned)d << 32) | (unsigned)src[i];
  }
}

// ---------------------------------------------------------------- embed ------
__global__ __launch_bounds__(256) void k_embed(
    const float* __restrict__ v, const float* __restrict__ r,
    const float* __restrict__ W1, const float* __restrict__ b1eff,
    const float* __restrict__ W2, const float* __restrict__ b2,
    float* __restrict__ h) {
  __shared__ float sIn[16][8];
  __shared__ float sW[32][128];
  __shared__ float sH[16][132];
  int tid = threadIdx.x;
  int n0 = blockIdx.x * 16;
  int tx = tid & 63, ty = tid >> 6;
  if (tid < 16 * 7) {
    int n = tid / 7, k = tid - n * 7;
    int gi = n0 + n;
    sIn[n][k] = (k == 0) ? r[gi] : v[gi * 6 + k - 1];
  }
  for (int idx = tid; idx < 7 * 128; idx += 256) sW[idx >> 7][idx & 127] = W1[idx];
  __syncthreads();
  float acc0[4], acc1[4];
  float bb0 = b1eff[tx], bb1 = b1eff[tx + 64];
#pragma unroll
  for (int i = 0; i < 4; i++) { acc0[i] = bb0; acc1[i] = bb1; }
  for (int k = 0; k < 7; k++) {
    float w0 = sW[k][tx], w1 = sW[k][tx + 64];
#pragma unroll
    for (int i = 0; i < 4; i++) {
      float a = sIn[ty * 4 + i][k];
      acc0[i] += a * w0; acc1[i] += a * w1;
    }
  }
  __syncthreads();
#pragma unroll
  for (int i = 0; i < 4; i++) {
    sH[ty * 4 + i][tx] = fmaxf(acc0[i], 0.f);
    sH[ty * 4 + i][tx + 64] = fmaxf(acc1[i], 0.f);
  }
  float bc0 = b2[tx], bc1 = b2[tx + 64];
#pragma unroll
  for (int i = 0; i < 4; i++) { acc0[i] = bc0; acc1[i] = bc1; }
  for (int k0 = 0; k0 < 128; k0 += 32) {
    __syncthreads();
    for (int idx = tid; idx < 32 * 128; idx += 256)
      sW[idx >> 7][idx & 127] = W2[(k0 + (idx >> 7)) * 128 + (idx & 127)];
    __syncthreads();
    for (int kk = 0; kk < 32; kk++) {
      float w0 = sW[kk][tx], w1 = sW[kk][tx + 64];
#pragma unroll
      for (int i = 0; i < 4; i++) {
        float a = sH[ty * 4 + i][k0 + kk];
        acc0[i] += a * w0; acc1[i] += a * w1;
      }
    }
  }
  for (int i = 0; i < 4; i++) {
    int gi = n0 + ty * 4 + i;
    h[gi * 128 + tx] = fmaxf(acc0[i], 0.f);
    h[gi * 128 + tx + 64] = fmaxf(acc1[i], 0.f);
  }
}

// ------------------------------------------------------------- node U/V ------
// U = hn@W1h + Qd + b1eff ; V = -hn@W1h + Qs, hn = (h-mean)*rsig. split-fp16 A.
__global__ __launch_bounds__(512) void k_uv(
    const float* __restrict__ h, const float* __restrict__ v, const float* __restrict__ r,
    const float* __restrict__ pos,
    const _Float16* __restrict__ wl, const float* __restrict__ W1,
    const float* __restrict__ b1eff,
    const float* __restrict__ mean, const float* __restrict__ rsig,
    float* __restrict__ U, float* __restrict__ Vv) {
  __shared__ char smem[32768];     // Ahi 16KB @0 | Alo 16KB @16384, swizzled
  __shared__ float sW1s[17][128];
  __shared__ float sNode[64][10];
  __shared__ float sMean[128], sRsig[128];
  int tid = threadIdx.x;
  int lane = tid & 63;
  int wid = __builtin_amdgcn_readfirstlane(tid >> 6);
  int n0 = blockIdx.x * 64;

  if (tid < 128) { sMean[tid] = mean[tid]; sRsig[tid] = rsig[tid]; }
  for (int idx = tid; idx < 17 * 128; idx += 512)
    sW1s[idx >> 7][idx & 127] = W1[(128 + (idx >> 7)) * HD + (idx & 127)];
  for (int idx = tid; idx < 640; idx += 512) {
    int n = idx / 10, j = idx - n * 10;
    int gn = n0 + n;
    float val = 0.f;
    if (gn < NN) val = (j < 6) ? v[gn * 6 + j] : (j == 6) ? r[gn] : pos[gn * 3 + (j - 7)];
    sNode[n][j] = val;
  }
  __syncthreads();
  // stage hn split-fp16 tile
#pragma unroll
  for (int it = 0; it < 2; it++) {
    int idx = tid + it * 512;
    int n = idx >> 4, kg = idx & 15;
    int gn = n0 + n;
    float4 a0 = {0,0,0,0}, a1 = {0,0,0,0};
    if (gn < NN) {
      const float4* hp = (const float4*)(h + (size_t)gn * 128 + kg * 8);
      a0 = hp[0]; a1 = hp[1];
    }
    int kb = kg * 8;
    h8 hv, lv;
#define SPLH(s, x, kkk) { float pv = ((x) - sMean[kkk]) * sRsig[kkk]; _Float16 hh = (_Float16)pv; hv[s] = hh; lv[s] = (_Float16)(pv - (float)hh); }
    SPLH(0, a0.x, kb+0) SPLH(1, a0.y, kb+1) SPLH(2, a0.z, kb+2) SPLH(3, a0.w, kb+3)
    SPLH(4, a1.x, kb+4) SPLH(5, a1.y, kb+5) SPLH(6, a1.z, kb+6) SPLH(7, a1.w, kb+7)
#undef SPLH
    int byteoff = (n * 256 + kg * 16) ^ ((n & 7) << 4);
    *(h8*)(smem + byteoff) = hv;
    *(h8*)(smem + 16384 + byteoff) = lv;
  }
  __syncthreads();

  h8 w1hi[4], w1lo[4];
#pragma unroll
  for (int ks = 0; ks < 4; ks++) {
    const _Float16* p = wl + (size_t)(ks * 8 + wid) * 1024 + lane * 8;
    w1hi[ks] = *(const h8*)p;
    w1lo[ks] = *(const h8*)(p + 512);
  }
  int arow = lane & 15, g4 = lane >> 4;
  f4 acc[4];
#pragma unroll
  for (int mt = 0; mt < 4; mt++) acc[mt] = (f4){0.f, 0.f, 0.f, 0.f};
#pragma unroll
  for (int ks = 0; ks < 4; ks++) {
#pragma unroll
    for (int mt = 0; mt < 4; mt++) {
      int row = mt * 16 + arow;
      int byte = (row * 256 + ks * 64 + g4 * 16) ^ ((row & 7) << 4);
      h8 ahi = *(const h8*)(smem + byte);
      h8 alo = *(const h8*)(smem + 16384 + byte);
      acc[mt] = __builtin_amdgcn_mfma_f32_16x16x32_f16(ahi, w1hi[ks], acc[mt], 0, 0, 0);
      acc[mt] = __builtin_amdgcn_mfma_f32_16x16x32_f16(ahi, w1lo[ks], acc[mt], 0, 0, 0);
      acc[mt] = __builtin_amdgcn_mfma_f32_16x16x32_f16(alo, w1hi[ks], acc[mt], 0, 0, 0);
    }
  }
  int cc = wid * 16 + arow;
  float b1v = b1eff[cc];
#pragma unroll
  for (int mt = 0; mt < 4; mt++) {
#pragma unroll
    for (int i = 0; i < 4; i++) {
      int n = mt * 16 + 4 * g4 + i;
      int gn = n0 + n;
      if (gn < NN) {
        float P = acc[mt][i];
        float qd = b1v, qs = 0.f;
#pragma unroll
        for (int j = 0; j < 6; j++) {
          float nv = sNode[n][j];
          qd += nv * sW1s[j][cc];
          qs += nv * sW1s[6 + j][cc];
        }
        float nr = sNode[n][6];
        qd += nr * sW1s[12][cc];
        qs += nr * sW1s[13][cc];
#pragma unroll
        for (int j = 0; j < 3; j++) {
          float pq = sNode[n][7 + j] * sW1s[14 + j][cc];
          qd += pq; qs -= pq;
        }
        U[(size_t)gn * 128 + cc] = P + qd;
        Vv[(size_t)gn * 128 + cc] = qs - P;
      }
    }
  }
}

// ---------------------------------------------------------------- message ----
// 64 sorted edges/block, 512 threads, 8 waves x 16 cols. split-fp16 A2, f32 sM.
__global__ __launch_bounds__(512) void k_msg3(
    const float* __restrict__ U, const float* __restrict__ Vv,
    const unsigned long long* __restrict__ es8,
    const _Float16* __restrict__ wl, const float* __restrict__ b2,
    float* __restrict__ agg) {
  __shared__ char smem[33792];   // A2hi @0 16KB, A2lo @16384 16KB; overlay sM f32 [64][132]
  __shared__ int sSrcA[64], sDstA[64];
  float* sM = (float*)smem;
  int tid = threadIdx.x;
  int lane = tid & 63;
  int wid = __builtin_amdgcn_readfirstlane(tid >> 6);
  size_t e0 = (size_t)blockIdx.x * 64;

  if (tid < 64) {
    unsigned long long w = es8[e0 + tid];
    sSrcA[tid] = (int)(w & 0xffffffffULL);
    sDstA[tid] = (int)(w >> 32);
  }
  h8 w2hi[4], w2lo[4];
#pragma unroll
  for (int ks = 0; ks < 4; ks++) {
    const _Float16* p = wl + (size_t)(40 + ks * 8 + wid) * 1024 + lane * 8;
    w2hi[ks] = *(const h8*)p;
    w2lo[ks] = *(const h8*)(p + 512);
  }
  __syncthreads();

  // stage A2 = split(relu(U[dst] + V[src])), swizzled
#pragma unroll
  for (int it = 0; it < 2; it++) {
    int c = tid + it * 512;
    int e = c >> 4, kg = c & 15;
    int dd = sDstA[e], ss = sSrcA[e];
    const float4* up = (const float4*)(U + (size_t)dd * 128 + kg * 8);
    const float4* vp = (const float4*)(Vv + (size_t)ss * 128 + kg * 8);
    float4 u0 = up[0], u1 = up[1];
    float4 v0 = vp[0], v1 = vp[1];
    h8 hv, lv;
#define SPL(s, x) { float pre = fmaxf((x), 0.f); _Float16 hh = (_Float16)pre; hv[s] = hh; lv[s] = (_Float16)(pre - (float)hh); }
    SPL(0, u0.x + v0.x) SPL(1, u0.y + v0.y) SPL(2, u0.z + v0.z) SPL(3, u0.w + v0.w)
    SPL(4, u1.x + v1.x) SPL(5, u1.y + v1.y) SPL(6, u1.z + v1.z) SPL(7, u1.w + v1.w)
#undef SPL
    int byteoff = (e * 256 + kg * 16) ^ ((e & 7) << 4);
    *(h8*)(smem + byteoff) = hv;
    *(h8*)(smem + 16384 + byteoff) = lv;
  }
  __syncthreads();

  int arow = lane & 15, g4 = lane >> 4;
  float b2v = b2[wid * 16 + arow];
  f4 acc[4];
#pragma unroll
  for (int mt = 0; mt < 4; mt++) acc[mt] = (f4){b2v, b2v, b2v, b2v};
#pragma unroll
  for (int ks = 0; ks < 4; ks++) {
#pragma unroll
    for (int mt = 0; mt < 4; mt++) {
      int row = mt * 16 + arow;
      int byte = (row * 256 + ks * 64 + g4 * 16) ^ ((row & 7) << 4);
      h8 ahi = *(const h8*)(smem + byte);
      h8 alo = *(const h8*)(smem + 16384 + byte);
      acc[mt] = __builtin_amdgcn_mfma_f32_16x16x32_f16(ahi, w2hi[ks], acc[mt], 0, 0, 0);
      acc[mt] = __builtin_amdgcn_mfma_f32_16x16x32_f16(ahi, w2lo[ks], acc[mt], 0, 0, 0);
      acc[mt] = __builtin_amdgcn_mfma_f32_16x16x32_f16(alo, w2hi[ks], acc[mt], 0, 0, 0);
    }
  }
  __syncthreads();  // A2 reads done; overlay sM
  int colc = wid * 16 + arow;
#pragma unroll
  for (int mt = 0; mt < 4; mt++)
#pragma unroll
    for (int i = 0; i < 4; i++) {
      int row = mt * 16 + 4 * g4 + i;
      sM[row * 132 + colc] = fmaxf(acc[mt][i], 0.f);
    }
  __syncthreads();

  // register-dedupe scatter (sorted by dst)
  int f = tid & 127, g = tid >> 7;
  float racc = 0.f;
  int prev = -1;
  for (int e = g * 16; e < g * 16 + 16; e++) {
    int d = sDstA[e];
    if (d != prev) {
      if (prev >= 0) atomicAdd(&agg[(size_t)prev * 128 + f], racc);
      racc = 0.f;
      prev = d;
    }
    racc += sM[e * 132 + f];
  }
  atomicAdd(&agg[(size_t)prev * 128 + f], racc);
}

// ---------------------------------------------------------------- update -----
// MFMA update MLP, split-fp16: A = [hn | agg*deginv] [64][256]; residual + stats.
__global__ __launch_bounds__(512) void k_upd2(
    float* __restrict__ h, const float* __restrict__ agg, const float* __restrict__ deginv,
    const _Float16* __restrict__ wl, const float* __restrict__ b1eff,
    const float* __restrict__ b2,
    const float* __restrict__ mean, const float* __restrict__ rsig,
    float* __restrict__ colsum, float* __restrict__ colsumsq) {
  __shared__ char smem[65536];   // Ahi @0 32KB, Alo @32768 32KB; later A2hi @0, A2lo @16384, red @32768
  __shared__ float sMean[128], sRsig[128];
  int tid = threadIdx.x;
  int lane = tid & 63;
  int wid = __builtin_amdgcn_readfirstlane(tid >> 6);
  int n0 = blockIdx.x * 64;
  if (tid < 128) { sMean[tid] = mean[tid]; sRsig[tid] = rsig[tid]; }
  __syncthreads();
  // stage A split-fp16
#pragma unroll
  for (int it = 0; it < 4; it++) {
    int c = tid + it * 512;
    int n = c >> 5, kg = c & 31;
    int gn = n0 + n;
    h8 hv, lv;
    if (gn < NN) {
      if (kg < 16) {
        const float4* hp = (const float4*)(h + (size_t)gn * 128 + kg * 8);
        float4 a0 = hp[0], a1 = hp[1];
        int kb = kg * 8;
#define SPLH(s, x, kkk) { float pv = ((x) - sMean[kkk]) * sRsig[kkk]; _Float16 hh = (_Float16)pv; hv[s] = hh; lv[s] = (_Float16)(pv - (float)hh); }
        SPLH(0, a0.x, kb+0) SPLH(1, a0.y, kb+1) SPLH(2, a0.z, kb+2) SPLH(3, a0.w, kb+3)
        SPLH(4, a1.x, kb+4) SPLH(5, a1.y, kb+5) SPLH(6, a1.z, kb+6) SPLH(7, a1.w, kb+7)
#undef SPLH
      } else {
        float dg = deginv[gn];
        const float4* ap = (const float4*)(agg + (size_t)gn * 128 + (kg - 16) * 8);
        float4 a0 = ap[0], a1 = ap[1];
#define SPLA(s, x) { float pv = (x) * dg; _Float16 hh = (_Float16)pv; hv[s] = hh; lv[s] = (_Float16)(pv - (float)hh); }
        SPLA(0, a0.x) SPLA(1, a0.y) SPLA(2, a0.z) SPLA(3, a0.w)
        SPLA(4, a1.x) SPLA(5, a1.y) SPLA(6, a1.z) SPLA(7, a1.w)
#undef SPLA
      }
    } else {
#pragma unroll
      for (int j = 0; j < 8; j++) { hv[j] = (_Float16)0.f; lv[j] = (_Float16)0.f; }
    }
    int byteoff = (n * 512 + kg * 16) ^ ((n & 7) << 4);
    *(h8*)(smem + byteoff) = hv;
    *(h8*)(smem + 32768 + byteoff) = lv;
  }
  __syncthreads();

  int arow = lane & 15, g4 = lane >> 4;
  int colc = wid * 16 + arow;
  float b1v = b1eff[colc];
  f4 acc[4];
#pragma unroll
  for (int mt = 0; mt < 4; mt++) acc[mt] = (f4){b1v, b1v, b1v, b1v};
  // GEMM1: K=256, two register phases of 4 ks
#pragma unroll
  for (int ksb = 0; ksb < 2; ksb++) {
    h8 whi[4], wlo[4];
#pragma unroll
    for (int kk = 0; kk < 4; kk++) {
      const _Float16* p = wl + (size_t)((ksb * 4 + kk) * 8 + wid) * 1024 + lane * 8;
      whi[kk] = *(const h8*)p;
      wlo[kk] = *(const h8*)(p + 512);
    }
#pragma unroll
    for (int kk = 0; kk < 4; kk++) {
#pragma unroll
      for (int mt = 0; mt < 4; mt++) {
        int row = mt * 16 + arow;
        int byte = (row * 512 + (ksb * 4 + kk) * 64 + g4 * 16) ^ ((row & 7) << 4);
        h8 ahi = *(const h8*)(smem + byte);
        h8 alo = *(const h8*)(smem + 32768 + byte);
        acc[mt] = __builtin_amdgcn_mfma_f32_16x16x32_f16(ahi, whi[kk], acc[mt], 0, 0, 0);
        acc[mt] = __builtin_amdgcn_mfma_f32_16x16x32_f16(ahi, wlo[kk], acc[mt], 0, 0, 0);
        acc[mt] = __builtin_amdgcn_mfma_f32_16x16x32_f16(alo, whi[kk], acc[mt], 0, 0, 0);
      }
    }
  }
  __syncthreads();  // A reads done
  // write hidden A2 split-fp16 [64][128]: hi @0, lo @16384
#pragma unroll
  for (int mt = 0; mt < 4; mt++)
#pragma unroll
    for (int i = 0; i < 4; i++) {
      int row = mt * 16 + 4 * g4 + i;
      int byte = (row * 256 + colc * 2) ^ ((row & 7) << 4);
      float hvf = fmaxf(acc[mt][i], 0.f);
      _Float16 hh = (_Float16)hvf;
      *(_Float16*)(smem + byte) = hh;
      *(_Float16*)(smem + 16384 + byte) = (_Float16)(hvf - (float)hh);
    }
  __syncthreads();
  // GEMM2
  float b2v = b2[colc];
  f4 acc2[4];
#pragma unroll
  for (int mt = 0; mt < 4; mt++) acc2[mt] = (f4){b2v, b2v, b2v, b2v};
  {
    h8 whi[4], wlo[4];
#pragma unroll
    for (int kk = 0; kk < 4; kk++) {
      const _Float16* p = wl + (size_t)(64 + kk * 8 + wid) * 1024 + lane * 8;
      whi[kk] = *(const h8*)p;
      wlo[kk] = *(const h8*)(p + 512);
    }
#pragma unroll
    for (int kk = 0; kk < 4; kk++) {
#pragma unroll
      for (int mt = 0; mt < 4; mt++) {
        int row = mt * 16 + arow;
        int byte = (row * 256 + kk * 64 + g4 * 16) ^ ((row & 7) << 4);
        h8 ahi = *(const h8*)(smem + byte);
        h8 alo = *(const h8*)(smem + 16384 + byte);
        acc2[mt] = __builtin_amdgcn_mfma_f32_16x16x32_f16(ahi, whi[kk], acc2[mt], 0, 0, 0);
        acc2[mt] = __builtin_amdgcn_mfma_f32_16x16x32_f16(ahi, wlo[kk], acc2[mt], 0, 0, 0);
        acc2[mt] = __builtin_amdgcn_mfma_f32_16x16x32_f16(alo, whi[kk], acc2[mt], 0, 0, 0);
      }
    }
  }
  // epilogue: residual (exact f32 from global) + writeback + stats
  float s = 0.f, q = 0.f;
  float mc = sMean[colc], rc = sRsig[colc];
#pragma unroll
  for (int mt = 0; mt < 4; mt++) {
#pragma unroll
    for (int i = 0; i < 4; i++) {
      int row = mt * 16 + 4 * g4 + i;
      int gn = n0 + row;
      if (gn < NN) {
        float hraw = h[(size_t)gn * 128 + colc];
        float hn = (hraw - mc) * rc;
        float hv = hn + fmaxf(acc2[mt][i], 0.f);
        h[(size_t)gn * 128 + colc] = hv;
        s += hv; q += hv * hv;
      }
    }
  }
  __syncthreads();  // all LDS reads done; red overlay @32768
  float* red = (float*)(smem + 32768);
  red[(colc * 4 + g4) * 2 + 0] = s;
  red[(colc * 4 + g4) * 2 + 1] = q;
  __syncthreads();
  if (tid < 128) {
    float ss = 0.f, qq = 0.f;
#pragma unroll
    for (int g = 0; g < 4; g++) { ss += red[(tid * 4 + g) * 2]; qq += red[(tid * 4 + g) * 2 + 1]; }
    atomicAdd(&colsum[tid], ss);
    atomicAdd(&colsumsq[tid], qq);
  }
}

// ---------------------------------------------------------------- output -----
__global__ __launch_bounds__(256) void k_out(
    const float* __restrict__ h, const float* __restrict__ pos, const float* __restrict__ v,
    const float* __restrict__ gf,
    const float* __restrict__ mean, const float* __restrict__ rsig,
    const float* __restrict__ W1, const float* __restrict__ b1,
    const float* __restrict__ W2, const float* __restrict__ b2,
    float* __restrict__ out) {
  __shared__ float sH[16][132];
  __shared__ float sW[32][128];
  __shared__ float sMean[128], sRsig[128];
  int tid = threadIdx.x;
  int n0 = blockIdx.x * 16;
  int tx = tid & 63, ty = tid >> 6;
  if (tid < 128) { sMean[tid] = mean[tid]; sRsig[tid] = rsig[tid]; }
  __syncthreads();
  for (int idx = tid; idx < 16 * 128; idx += 256) {
    int n = idx >> 7, k = idx & 127;
    sH[n][k] = (h[(size_t)(n0 + n) * 128 + k] - sMean[k]) * sRsig[k];
  }
  float acc0[4], acc1[4];
  float bb0 = b1[tx], bb1 = b1[tx + 64];
#pragma unroll
  for (int i = 0; i < 4; i++) { acc0[i] = bb0; acc1[i] = bb1; }
  for (int k0 = 0; k0 < 128; k0 += 32) {
    __syncthreads();
    for (int idx = tid; idx < 32 * 128; idx += 256)
      sW[idx >> 7][idx & 127] = W1[(k0 + (idx >> 7)) * 128 + (idx & 127)];
    __syncthreads();
    for (int kk = 0; kk < 32; kk++) {
      float w0 = sW[kk][tx], w1 = sW[kk][tx + 64];
#pragma unroll
      for (int i = 0; i < 4; i++) {
        float a = sH[ty * 4 + i][k0 + kk];
        acc0[i] += a * w0; acc1[i] += a * w1;
      }
    }
  }
  __syncthreads();
#pragma unroll
  for (int i = 0; i < 4; i++) {
    sH[ty * 4 + i][tx] = fmaxf(acc0[i], 0.f);
    sH[ty * 4 + i][tx + 64] = fmaxf(acc1[i], 0.f);
  }
  __syncthreads();
  if (tid < 144) {
    int n = tid / 9, j = tid - n * 9;
    float a = b2[j];
    for (int k = 0; k < 128; k++) a += sH[n][k] * W2[k * 9 + j];
    int gi = n0 + n;
    if (j < 3) {
      float p = a + pos[gi * 3 + j];
      float d = gf[5 + j];
      float m = fmodf(p, d);
      if (m < 0.f) m += d;
      out[(size_t)gi * 3 + j] = m;
    } else {
      float p = a + v[gi * 6 + (j - 3)];
      out[(size_t)NN * 3 + (size_t)gi * 6 + (j - 3)] = p;
    }
  }
}

// h_mean of normalized h is ~0 -> macro = relu(b1)@W2 + b2
__global__ void k_macro(const float* __restrict__ b1,
                        const float* __restrict__ W2, const float* __restrict__ b2,
                        float* __restrict__ out) {
  __shared__ float hid[128];
  int f = threadIdx.x;
  hid[f] = fmaxf(b1[f], 0.f);
  __syncthreads();
  if (f < 4) {
    float a = b2[f];
    for (int k = 0; k < 128; k++) a += hid[k] * W2[k * 4 + f];
    out[(size_t)NN * 9 + f] = a;
  }
}

// ------------------------------------------------------------------ host -----
extern "C" void kernel_launch(void* const* d_in, const int* in_sizes, int n_in,
                              void* d_out, int out_size, void* d_ws, size_t ws_size,
                              hipStream_t stream) {
  (void)in_sizes; (void)n_in; (void)out_size; (void)ws_size;
  const float* v    = (const float*)d_in[0];
  const float* pos  = (const float*)d_in[1];
  const float* r    = (const float*)d_in[2];
  const float* dom  = (const float*)d_in[3];
  const float* t    = (const float*)d_in[4];
  const float* domn = (const float*)d_in[5];
  const float* tn   = (const float*)d_in[6];
  const int*   eidx = (const int*)d_in[7];
  const float* embW1 = (const float*)d_in[9];
  const float* embb1 = (const float*)d_in[10];
  const float* embW2 = (const float*)d_in[11];
  const float* embb2 = (const float*)d_in[12];
  const float* msgW1 = (const float*)d_in[13];
  const float* msgb1 = (const float*)d_in[14];
  const float* msgW2 = (const float*)d_in[15];
  const float* msgb2 = (const float*)d_in[16];
  const float* updW1 = (const float*)d_in[17];
  const float* updb1 = (const float*)d_in[18];
  const float* updW2 = (const float*)d_in[19];
  const float* updb2 = (const float*)d_in[20];
  const float* outW1 = (const float*)d_in[21];
  const float* outb1 = (const float*)d_in[22];
  const float* outW2 = (const float*)d_in[23];
  const float* outb2 = (const float*)d_in[24];
  const float* macb1 = (const float*)d_in[26];
  const float* macW2 = (const float*)d_in[27];
  const float* macb2 = (const float*)d_in[28];

  const int* srcp = eidx;
  const int* dstp = eidx + NE;

  char* ws = (char*)d_ws;
  float* h        = (float*)(ws);                   // 25.6 MB
  float* agg      = (float*)(ws + 25600000);        // 25.6 MB
  float* U        = (float*)(ws + 51200000);        // 25.6 MB
  float* Vv       = (float*)(ws + 76800000);        // 25.6 MB
  unsigned long long* es8 = (unsigned long long*)(ws + 102400000);  // 12.8 MB
  int*   degi     = (int*)(ws + 115200000);
  float* deginv   = (float*)(ws + 115400000);
  int*   cursor   = (int*)(ws + 115600000);
  float* gf       = (float*)(ws + 115800000);
  float* beff     = (float*)(ws + 115800064);
  float* colsum   = (float*)(ws + 115806720);
  float* colsumsq = (float*)(ws + 115807232);
  float* meanb    = (float*)(ws + 115807744);
  float* rsigb    = (float*)(ws + 115808256);
  _Float16* wpack = (_Float16*)(ws + 115808768);    // 2064384 B
  float* outp     = (float*)d_out;

  k_prep<<<1, 64, 0, stream>>>(dom, t, domn, tn, gf);
  k_bias<<<13, 128, 0, stream>>>(gf, msgW1, msgb1, updW1, updb1, embW1, embb1, beff);
  k_wpack<<<1008, 64, 0, stream>>>(msgW1, msgW2, updW1, updW2, wpack);
  k_initnorm<<<1, 128, 0, stream>>>(meanb, rsigb);

  hipMemsetAsync(degi, 0, NN * sizeof(int), stream);
  k_degi<<<4096, 256, 0, stream>>>(dstp, degi);
  k_deginv<<<(NN + 255) / 256, 256, 0, stream>>>(degi, deginv);
  k_scan<<<1, 1024, 0, stream>>>(degi, cursor);
  k_scatter<<<6250, 256, 0, stream>>>(srcp, dstp, cursor, es8);

  k_embed<<<NN / 16, 256, 0, stream>>>(v, r, embW1, beff + 12 * HD, embW2, embb2, h);

  for (int l = 0; l < NL; l++) {
    k_uv<<<(NN + 63) / 64, 512, 0, stream>>>(h, v, r, pos,
                                             wpack + (size_t)l * 73728,
                                             msgW1 + (size_t)l * 155 * HD,
                                             beff + l * HD, meanb, rsigb, U, Vv);
    hipMemsetAsync(agg, 0, (size_t)NN * 128 * sizeof(float), stream);
    hipMemsetAsync(colsum, 0, 1024, stream);
    k_msg3<<<NE / 64, 512, 0, stream>>>(U, Vv, es8,
                                        wpack + (size_t)l * 73728,
                                        msgb2 + l * HD, agg);
    k_upd2<<<(NN + 63) / 64, 512, 0, stream>>>(h, agg, deginv,
                                               wpack + UPD_OFF + (size_t)l * 98304,
                                               beff + (6 + l) * HD, updb2 + l * HD,
                                               meanb, rsigb, colsum, colsumsq);
    k_stats<<<1, 128, 0, stream>>>(colsum, colsumsq, meanb, rsigb);
  }

  k_out<<<NN / 16, 256, 0, stream>>>(h, pos, v, gf, meanb, rsigb,
                                     outW1, outb1, outW2, outb2, outp);
  k_macro<<<1, 128, 0, stream>>>(macb1, macW2, macb2, outp);
}